// Round 10
// baseline (29691.467 us; speedup 1.0000x reference)
//
#include <hip/hip_runtime.h>
#include <hip/hip_cooperative_groups.h>
#include <math.h>

namespace cg = cooperative_groups;

#define BATCH 8192
#define KB 2048      // num basis (N of fused GEMM)
#define DD 1024      // dim basis
#define LAM 0.1f
#define N_ITER 100
#define N_POWER 50
#define NTILES 96    // K' = 6144 = 96 * 64

typedef unsigned short u16;
using short8 = __attribute__((ext_vector_type(8))) short;
using f32x4  = __attribute__((ext_vector_type(4))) float;

// ---------- bf16 split helpers (RNE) ----------
__device__ __forceinline__ u16 f2bf(float f) {
  unsigned int u = __builtin_bit_cast(unsigned int, f);
  u = u + 0x7FFFu + ((u >> 16) & 1u);
  return (u16)(u >> 16);
}
__device__ __forceinline__ float bf2f(u16 s) {
  unsigned int u = ((unsigned int)s) << 16;
  return __builtin_bit_cast(float, u);
}

// ---------------- utility kernels ----------------
__global__ void k_split_f32(const float* __restrict__ in, u16* __restrict__ h,
                            u16* __restrict__ lo, int n) {
  for (int i = blockIdx.x * blockDim.x + threadIdx.x; i < n; i += gridDim.x * blockDim.x) {
    float v = in[i];
    u16 hh = f2bf(v);
    h[i] = hh;
    lo[i] = f2bf(v - bf2f(hh));
  }
}

__global__ void k_zero2(float4* __restrict__ a, int na, float4* __restrict__ b, int nb) {
  float4 z = {0.f, 0.f, 0.f, 0.f};
  for (int i = blockIdx.x * blockDim.x + threadIdx.x; i < na; i += gridDim.x * blockDim.x)
    a[i] = z;
  for (int i = blockIdx.x * blockDim.x + threadIdx.x; i < nb; i += gridDim.x * blockDim.x)
    b[i] = z;
}

__global__ void k_init_v(float* __restrict__ v) {
  int i = blockIdx.x * blockDim.x + threadIdx.x;
  if (i < KB) v[i] = 1.f;
}

// ---------------- power iteration (proven r3) ----------------
template <int MODE>
__global__ __launch_bounds__(256) void k_power_matvec(const float* __restrict__ G,
                                                      const float* __restrict__ vin,
                                                      float* __restrict__ wout,
                                                      float* __restrict__ partial) {
  int rloc = threadIdx.x >> 3;
  int seg = threadIdx.x & 7;
  int row = blockIdx.x * 32 + rloc;
  const float* g = G + (size_t)row * KB + seg * 256;
  const float* vv = vin + seg * 256;
  float s = 0.f;
#pragma unroll 8
  for (int j = 0; j < 256; j += 4) {
    float4 gg = *(const float4*)(g + j);
    float4 vx = *(const float4*)(vv + j);
    s = fmaf(gg.x, vx.x, fmaf(gg.y, vx.y, fmaf(gg.z, vx.z, fmaf(gg.w, vx.w, s))));
  }
#pragma unroll
  for (int off = 1; off < 8; off <<= 1) s += __shfl_xor(s, off, 64);
  if (seg == 0) wout[row] = s;
  float val = (seg == 0) ? (MODE ? vin[row] * s : s * s) : 0.f;
#pragma unroll
  for (int off = 8; off < 64; off <<= 1) val += __shfl_xor(val, off, 64);
  __shared__ float red[4];
  int lane = threadIdx.x & 63, wid = threadIdx.x >> 6;
  if (lane == 0) red[wid] = val;
  __syncthreads();
  if (threadIdx.x == 0) partial[blockIdx.x] = red[0] + red[1] + red[2] + red[3];
}

__global__ void k_power_scale(const float* __restrict__ w, float* __restrict__ v,
                              const float* __restrict__ partial) {
  float n2 = 0.f;
#pragma unroll
  for (int i = 0; i < 64; ++i) n2 += partial[i];
  int i = blockIdx.x * 256 + threadIdx.x;
  v[i] = w[i] / sqrtf(n2);
}

__global__ void k_compute_step(const float* __restrict__ partialL, float* __restrict__ stepbuf) {
  float L = 0.f;
#pragma unroll
  for (int i = 0; i < 64; ++i) L += partialL[i];
  stepbuf[0] = 1.f / L;
}

// ---------------- Cx = x @ phi^T (split-bf16 MFMA, fp32 out; r3-proven structure) ----------------
__global__ __launch_bounds__(256) void k_xphiT(
    const u16* __restrict__ Ah, const u16* __restrict__ Al,
    const u16* __restrict__ Bh, const u16* __restrict__ Bl,
    float* __restrict__ Cout, int N, int K) {
  __shared__ u16 lds[4 * 128 * 32];
  const int tid = threadIdx.x;
  const int w = tid >> 6, l = tid & 63;
  const int row0 = blockIdx.y * 128, col0 = blockIdx.x * 128;
  const int wm = (w >> 1) * 64, wn = (w & 1) * 64;
  const int lrow = l & 15, lk = (l >> 4) * 8;

  f32x4 zero4 = {0.f, 0.f, 0.f, 0.f};
  f32x4 acc[4][4];
#pragma unroll
  for (int i = 0; i < 4; ++i)
#pragma unroll
    for (int j = 0; j < 4; ++j) acc[i][j] = zero4;

  for (int k0 = 0; k0 < K; k0 += 32) {
    {
      const u16* gs[4] = {Ah, Al, Bh, Bl};
      const int r0s[4] = {row0, row0, col0, col0};
#pragma unroll
      for (int st = 0; st < 4; ++st) {
        u16* s = lds + st * 4096;
#pragma unroll
        for (int h = 0; h < 2; ++h) {
          int ch = h * 256 + w * 64 + l;
          const u16* gp = gs[st] + (size_t)(r0s[st] + (ch >> 2)) * K + k0 + (ch & 3) * 8;
          u16* sp = s + (h * 256 + w * 64) * 8;
          __builtin_amdgcn_global_load_lds((const __attribute__((address_space(1))) void*)gp,
                                           (__attribute__((address_space(3))) void*)sp, 16, 0, 0);
        }
      }
    }
    __syncthreads();
    short8 ah[4], al[4];
#pragma unroll
    for (int i = 0; i < 4; ++i) {
      int r = wm + i * 16 + lrow;
      ah[i] = *(const short8*)&lds[0 * 4096 + r * 32 + lk];
      al[i] = *(const short8*)&lds[1 * 4096 + r * 32 + lk];
    }
#pragma unroll
    for (int j = 0; j < 4; ++j) {
      int r = wn + j * 16 + lrow;
      short8 bh = *(const short8*)&lds[2 * 4096 + r * 32 + lk];
      short8 bl = *(const short8*)&lds[3 * 4096 + r * 32 + lk];
#pragma unroll
      for (int i = 0; i < 4; ++i) {
        acc[i][j] = __builtin_amdgcn_mfma_f32_16x16x32_bf16(ah[i], bh, acc[i][j], 0, 0, 0);
        acc[i][j] = __builtin_amdgcn_mfma_f32_16x16x32_bf16(ah[i], bl, acc[i][j], 0, 0, 0);
        acc[i][j] = __builtin_amdgcn_mfma_f32_16x16x32_bf16(al[i], bh, acc[i][j], 0, 0, 0);
      }
    }
    __syncthreads();
  }
#pragma unroll
  for (int i = 0; i < 4; ++i)
#pragma unroll
    for (int r = 0; r < 4; ++r) {
      int m = row0 + wm + i * 16 + ((l >> 4) << 2) + r;
      size_t base = (size_t)m * N;
#pragma unroll
      for (int j = 0; j < 4; ++j) {
        int n = col0 + wn + j * 16 + (l & 15);
        Cout[base + n] = acc[i][j][r];
      }
    }
}

// ---------------- fp32 GEMMs (one-time: Gram, recon; proven r3) ----------------
#define BM 128
#define BN 128
#define BKK 16

__global__ __launch_bounds__(256) void k_gram_f32(const float* __restrict__ A,
                                                  const float* __restrict__ Bt,
                                                  float* __restrict__ C, int M, int N, int Kd) {
  __shared__ float As[BKK][BM + 4];
  __shared__ float Bs[BKK][BN + 4];
  int tx = threadIdx.x & 15, ty = threadIdx.x >> 4;
  int row0 = blockIdx.y * BM, col0 = blockIdx.x * BN;
  float acc[8][8] = {};
  for (int k0 = 0; k0 < Kd; k0 += BKK) {
#pragma unroll
    for (int i = 0; i < 2; ++i) {
      int f = threadIdx.x + 256 * i;
      int r = f >> 2, kk = (f & 3) << 2;
      float4 a = *(const float4*)&A[(size_t)(row0 + r) * Kd + k0 + kk];
      As[kk + 0][r] = a.x; As[kk + 1][r] = a.y; As[kk + 2][r] = a.z; As[kk + 3][r] = a.w;
      float4 b = *(const float4*)&Bt[(size_t)(col0 + r) * Kd + k0 + kk];
      Bs[kk + 0][r] = b.x; Bs[kk + 1][r] = b.y; Bs[kk + 2][r] = b.z; Bs[kk + 3][r] = b.w;
    }
    __syncthreads();
#pragma unroll
    for (int k = 0; k < BKK; ++k) {
      float a[8], b[8];
      *(float4*)&a[0] = *(const float4*)&As[k][ty * 8];
      *(float4*)&a[4] = *(const float4*)&As[k][ty * 8 + 4];
      *(float4*)&b[0] = *(const float4*)&Bs[k][tx * 8];
      *(float4*)&b[4] = *(const float4*)&Bs[k][tx * 8 + 4];
#pragma unroll
      for (int i = 0; i < 8; ++i)
#pragma unroll
        for (int j = 0; j < 8; ++j) acc[i][j] = fmaf(a[i], b[j], acc[i][j]);
    }
    __syncthreads();
  }
  int m0 = row0 + ty * 8, n0 = col0 + tx * 8;
#pragma unroll
  for (int i = 0; i < 8; ++i)
#pragma unroll
    for (int j4 = 0; j4 < 2; ++j4) {
      float4 c;
      c.x = acc[i][j4 * 4 + 0]; c.y = acc[i][j4 * 4 + 1];
      c.z = acc[i][j4 * 4 + 2]; c.w = acc[i][j4 * 4 + 3];
      *(float4*)&C[(size_t)(m0 + i) * N + n0 + j4 * 4] = c;
    }
}

__global__ __launch_bounds__(256) void k_recon_f32(const float* __restrict__ A,
                                                   const float* __restrict__ Bm,
                                                   float* __restrict__ C, int M, int N, int Kd) {
  __shared__ float As[BKK][BM + 4];
  __shared__ float Bs[BKK][BN + 4];
  int tx = threadIdx.x & 15, ty = threadIdx.x >> 4;
  int row0 = blockIdx.y * BM, col0 = blockIdx.x * BN;
  float acc[8][8] = {};
  for (int k0 = 0; k0 < Kd; k0 += BKK) {
#pragma unroll
    for (int i = 0; i < 2; ++i) {
      int f = threadIdx.x + 256 * i;
      int r = f >> 2, kk = (f & 3) << 2;
      float4 a = *(const float4*)&A[(size_t)(row0 + r) * Kd + k0 + kk];
      As[kk + 0][r] = a.x; As[kk + 1][r] = a.y; As[kk + 2][r] = a.z; As[kk + 3][r] = a.w;
      int kr = f >> 5, nc = (f & 31) << 2;
      *(float4*)&Bs[kr][nc] = *(const float4*)&Bm[(size_t)(k0 + kr) * N + col0 + nc];
    }
    __syncthreads();
#pragma unroll
    for (int k = 0; k < BKK; ++k) {
      float a[8], b[8];
      *(float4*)&a[0] = *(const float4*)&As[k][ty * 8];
      *(float4*)&a[4] = *(const float4*)&As[k][ty * 8 + 4];
      *(float4*)&b[0] = *(const float4*)&Bs[k][tx * 8];
      *(float4*)&b[4] = *(const float4*)&Bs[k][tx * 8 + 4];
#pragma unroll
      for (int i = 0; i < 8; ++i)
#pragma unroll
        for (int j = 0; j < 8; ++j) acc[i][j] = fmaf(a[i], b[j], acc[i][j]);
    }
    __syncthreads();
  }
  int m0 = row0 + ty * 8, n0 = col0 + tx * 8;
#pragma unroll
  for (int i = 0; i < 8; ++i)
#pragma unroll
    for (int j4 = 0; j4 < 2; ++j4) {
      float4 c;
      c.x = acc[i][j4 * 4 + 0]; c.y = acc[i][j4 * 4 + 1];
      c.z = acc[i][j4 * 4 + 2]; c.w = acc[i][j4 * 4 + 3];
      *(float4*)&C[(size_t)(m0 + i) * N + n0 + j4 * 4] = c;
    }
}

// ---------------- fused FISTA iteration (cooperative) ----------------
// acc = y @ G  over logical K' = 6144 (segments: yh*Gh | yl*Gh | yh*Gl),
// grid.sync, then in-place FISTA update of (Alpha, Yh, Yl).
// 256x256 tile, BK=64, 8 waves (2Mx4N), double-buffered 128KB static LDS,
// counted vmcnt(8), XOR bank swizzle, T1 XCD remap, T5 setprio.
//
// r9 evidence: T1 remap cut FETCH 595->332 MB/iter but dur only -3% ->
// schedule-bound. This round: m201-style 4-phase K-tile (T3). Each phase:
// {8 ds_read_b128; s_barrier; lgkmcnt(0); setprio(1); 16 MFMA; setprio(0);
// s_barrier} - phase barriers decouple LDS-pipe fill from MFMA-pipe drain
// across the 8 waves. Staging stays at tile end (2-buffer LDS: staging
// mid-tile would overwrite the buffer being consumed) with counted vmcnt(8).

__device__ __forceinline__ void stage_op(const u16* src, int r0, int q0,
                                         u16* ldsbase, int tid) {
#pragma unroll
  for (int i = 0; i < 4; ++i) {
    int c = i * 512 + tid;
    int r = c >> 3;
    int sp = (c & 7) ^ (r & 7);
    const u16* gp = src + ((size_t)(r0 + r) << 11) + (q0 + (sp << 3));
    u16* lp = ldsbase + ((i * 512 + (tid & 448)) << 3);  // wave-uniform base
    __builtin_amdgcn_global_load_lds((const __attribute__((address_space(1))) void*)gp,
                                     (__attribute__((address_space(3))) void*)lp, 16, 0, 0);
  }
}

__global__ __launch_bounds__(512, 1) void k_fista_fused(
    u16* Yh, u16* Yl,
    const u16* __restrict__ Gh, const u16* __restrict__ Gl,
    const float* __restrict__ Cx, float* Alpha,
    const float* __restrict__ stepbuf, float mu) {
  __shared__ u16 lds[65536];  // 128 KB static: [buf][A 16384 u16 | B 16384 u16]

  const int tid = threadIdx.x;
  const int w = tid >> 6, l = tid & 63;
  const int wm = w >> 2, wn = w & 3;       // 2 x 4 waves
  const int lr = l & 15, lg = l >> 4;

  // XCD-aware remap (r9-verified: FETCH 595->332 MB/iter).
  const int lin = blockIdx.x + (int)gridDim.x * blockIdx.y;  // [0,256)
  const int bq = lin >> 6;          // [0,4)
  const int bp = (lin >> 3) & 7;    // [0,8)
  const int br = lin & 7;           // [0,8)
  const int row0 = ((bq << 3) + br) * 256;  // by = 8q + r
  const int col0 = bp * 256;                // bx = p

  f32x4 acc[8][4];
  f32x4 zero4 = {0.f, 0.f, 0.f, 0.f};
#pragma unroll
  for (int i = 0; i < 8; ++i)
#pragma unroll
    for (int j = 0; j < 4; ++j) acc[i][j] = zero4;

  // prologue: stage tiles 0 (buf0) and 1 (buf1); both in segment 0 (Yh/Gh)
  stage_op(Yh, row0, 0, lds, tid);
  stage_op(Gh, col0, 0, lds + 16384, tid);
  stage_op(Yh, row0, 64, lds + 32768, tid);
  stage_op(Gh, col0, 64, lds + 49152, tid);

// one phase: ds_read subtile -> barrier -> lgkm drain -> 16 MFMA -> barrier
#define PHASE(KS, IH)                                                             \
  {                                                                               \
    short8 af[4], bfr[4];                                                         \
    _Pragma("unroll") for (int q = 0; q < 4; ++q) {                               \
      int arow = wm * 128 + ((IH) * 4 + q) * 16 + lr;                             \
      af[q] = *(const short8*)(baseA + arow * 64 + ((((KS) * 4 + lg) ^ (arow & 7)) << 3)); \
      int brow = wn * 64 + q * 16 + lr;                                           \
      bfr[q] = *(const short8*)(baseB + brow * 64 + ((((KS) * 4 + lg) ^ (brow & 7)) << 3)); \
    }                                                                             \
    __builtin_amdgcn_s_barrier();                                                 \
    asm volatile("s_waitcnt lgkmcnt(0)" ::: "memory");                            \
    __builtin_amdgcn_sched_barrier(0);                                            \
    __builtin_amdgcn_s_setprio(1);                                                \
    _Pragma("unroll") for (int q = 0; q < 4; ++q) {                               \
      _Pragma("unroll") for (int j = 0; j < 4; ++j) {                             \
        acc[(IH) * 4 + q][j] = __builtin_amdgcn_mfma_f32_16x16x32_bf16(           \
            af[q], bfr[j], acc[(IH) * 4 + q][j], 0, 0, 0);                        \
      }                                                                           \
    }                                                                             \
    __builtin_amdgcn_s_setprio(0);                                                \
    __builtin_amdgcn_sched_barrier(0);                                            \
    __builtin_amdgcn_s_barrier();                                                 \
  }

#define FBODY(TT, B)                                                              \
  {                                                                               \
    asm volatile("s_waitcnt vmcnt(8)" ::: "memory");                              \
    __builtin_amdgcn_s_barrier();                                                 \
    const u16* baseA = lds + ((B) ? 32768 : 0);                                   \
    const u16* baseB = baseA + 16384;                                             \
    PHASE(0, 0)                                                                   \
    PHASE(0, 1)                                                                   \
    PHASE(1, 0)                                                                   \
    PHASE(1, 1)                                                                   \
    int tn = (TT) + 2;                                                            \
    if (tn >= NTILES) tn -= NTILES;                                               \
    int k0n = tn << 6;                                                            \
    int sg = k0n >> 11;                                                           \
    int q0 = k0n & 2047;                                                          \
    stage_op(sg == 1 ? Yl : Yh, row0, q0, lds + ((B) ? 32768 : 0), tid);          \
    stage_op(sg == 2 ? Gl : Gh, col0, q0, lds + ((B) ? 32768 : 0) + 16384, tid);  \
  }

  for (int tt = 0; tt < NTILES; tt += 2) {
    FBODY(tt, 0)
    FBODY(tt + 1, 1)
  }
#undef FBODY
#undef PHASE

  asm volatile("s_waitcnt vmcnt(0)" ::: "memory");
  cg::this_grid().sync();

  // ---- fused FISTA epilogue: each block updates only its own C-tile ----
  const float step = stepbuf[0];
  const float thr = LAM * step;
#pragma unroll
  for (int i = 0; i < 8; ++i) {
#pragma unroll
    for (int r = 0; r < 4; ++r) {
      int m = row0 + wm * 128 + i * 16 + (lg << 2) + r;
      size_t base = (size_t)m * KB;
#pragma unroll
      for (int j = 0; j < 4; ++j) {
        int n = col0 + wn * 64 + j * 16 + lr;
        size_t idx = base + n;
        float g = acc[i][j][r] - Cx[idx];
        float y = bf2f(Yh[idx]) + bf2f(Yl[idx]);
        float z = y - step * g;
        float az = fabsf(z) - thr;
        float a = az > 0.f ? copysignf(az, z) : 0.f;
        float ap = Alpha[idx];
        float yn = a + mu * (a - ap);
        Alpha[idx] = a;
        u16 hh = f2bf(yn);
        Yh[idx] = hh;
        Yl[idx] = f2bf(yn - bf2f(hh));
      }
    }
  }
}

// ---------------- launch ----------------
extern "C" void kernel_launch(void* const* d_in, const int* in_sizes, int n_in,
                              void* d_out, int out_size, void* d_ws, size_t ws_size,
                              hipStream_t stream) {
  const float* x = (const float*)d_in[0];    // [8192,1024]
  const float* phi = (const float*)d_in[1];  // [2048,1024]
  float* out = (float*)d_out;
  float* alpha = out;                             // [8192*2048] fp32, in-place FISTA state
  float* reconF = out + (size_t)BATCH * KB;       // [8192*1024] fp32 (33.55 MB scratch region)

  // ---- workspace layout (byte offsets) ----
  char* ws = (char*)d_ws;
  u16* Yh = (u16*)ws;                                   // 33,554,432 B
  u16* Yl = (u16*)(ws + 33554432ull);                   // 33,554,432 B
  u16* Gph = (u16*)(ws + 67108864ull);                  // 8,388,608 B  (G' hi; temp phiH)
  u16* Gpl = (u16*)(ws + 75497472ull);                  // 8,388,608 B  (G' lo; temp phiL)
  float* Cx = (float*)(ws + 83886080ull);               // 67,108,864 B
  float* stepbuf = (float*)(ws + 150994944ull);         // 64 B
  const size_t need = 150995008ull;
  if (ws_size < need) return;

  // pre-FISTA temporaries:
  float* Gf = (float*)Yh;           // G fp32 [2048][2048] = 16.78 MB in Yh/Yl region
  u16* xh = (u16*)reconF;           // x split hi [8192*1024]
  u16* xl = xh + (size_t)BATCH * DD;
  float* vbuf = reconF;             // power-iter scratch (after Cx done, xh/xl dead)
  float* wbuf = reconF + 2048;
  float* normPart = reconF + 4096;  // 50*64
  float* LPart = reconF + 7296;     // 64

  // 1. splits: phi -> (Gph,Gpl temp), x -> (xh,xl in recon region)
  k_split_f32<<<2048, 256, 0, stream>>>(phi, Gph, Gpl, KB * DD);
  k_split_f32<<<2048, 256, 0, stream>>>(x, xh, xl, BATCH * DD);

  // 2. Cx = x @ phi^T (fp32 out), M=8192 N=2048 K=1024
  k_xphiT<<<dim3(KB / 128, BATCH / 128), 256, 0, stream>>>(xh, xl, Gph, Gpl, Cx, KB, DD);

  // 3. G = phi @ phi^T (fp32) into Yh region
  k_gram_f32<<<dim3(KB / BN, KB / BM), 256, 0, stream>>>(phi, phi, Gf, KB, KB, DD);

  // 4. power iteration -> step = 1/L  (scratch in recon region; xh/xl dead)
  k_init_v<<<8, 256, 0, stream>>>(vbuf);
  for (int s = 0; s < N_POWER; ++s) {
    k_power_matvec<0><<<64, 256, 0, stream>>>(Gf, vbuf, wbuf, normPart + s * 64);
    k_power_scale<<<KB / 256, 256, 0, stream>>>(wbuf, vbuf, normPart + s * 64);
  }
  k_power_matvec<1><<<64, 256, 0, stream>>>(Gf, vbuf, wbuf, LPart);
  k_compute_step<<<1, 1, 0, stream>>>(LPart, stepbuf);

  // 5. G' = split(G) (overwrites phi splits; they are dead)
  k_split_f32<<<2048, 256, 0, stream>>>(Gf, Gph, Gpl, KB * KB);

  // 6. zero Y (kills G) and alpha
  k_zero2<<<2048, 256, 0, stream>>>((float4*)Yh, (int)(67108864 / 16),
                                    (float4*)alpha, (int)(67108864 / 16));

  // 7. FISTA: 100 cooperative fused iterations
  float t = 1.f;
  float mus[N_ITER];
  for (int it = 0; it < N_ITER; ++it) {
    float tn = 0.5f * (1.f + sqrtf(1.f + 4.f * t * t));
    mus[it] = (t - 1.f) / tn;
    t = tn;
  }
  u16 *pYh = Yh, *pYl = Yl;
  const u16 *pGh = Gph, *pGl = Gpl;
  const float* pCx = Cx;
  float* pAl = alpha;
  const float* pStep = stepbuf;
  for (int it = 0; it < N_ITER; ++it) {
    void* kargs[8] = {&pYh, &pYl, &pGh, &pGl, &pCx, &pAl, &pStep, &mus[it]};
    (void)hipLaunchCooperativeKernel((const void*)k_fista_fused, dim3(KB / 256, BATCH / 256),
                                     dim3(512), kargs, 0, stream);
  }

  // 8. recon = alpha @ phi (fp32; overwrites recon-region scratch)
  k_recon_f32<<<dim3(DD / BN, BATCH / BM), 256, 0, stream>>>(
      alpha, phi, reconF, BATCH, DD, KB);
}

// Round 11
// 26159.662 us; speedup vs baseline: 1.1350x; 1.1350x over previous
//
#include <hip/hip_runtime.h>
#include <hip/hip_cooperative_groups.h>
#include <math.h>

namespace cg = cooperative_groups;

#define BATCH 8192
#define KB 2048      // num basis (N of fused GEMM)
#define DD 1024      // dim basis
#define LAM 0.1f
#define N_ITER 100
#define N_POWER 50
#define NTILES 96    // K' = 6144 = 96 * 64

typedef unsigned short u16;
using short8 = __attribute__((ext_vector_type(8))) short;
using f32x4  = __attribute__((ext_vector_type(4))) float;

// ---------- bf16 split helpers (RNE) ----------
__device__ __forceinline__ u16 f2bf(float f) {
  unsigned int u = __builtin_bit_cast(unsigned int, f);
  u = u + 0x7FFFu + ((u >> 16) & 1u);
  return (u16)(u >> 16);
}
__device__ __forceinline__ float bf2f(u16 s) {
  unsigned int u = ((unsigned int)s) << 16;
  return __builtin_bit_cast(float, u);
}

// ---------------- utility kernels ----------------
__global__ void k_split_f32(const float* __restrict__ in, u16* __restrict__ h,
                            u16* __restrict__ lo, int n) {
  for (int i = blockIdx.x * blockDim.x + threadIdx.x; i < n; i += gridDim.x * blockDim.x) {
    float v = in[i];
    u16 hh = f2bf(v);
    h[i] = hh;
    lo[i] = f2bf(v - bf2f(hh));
  }
}

__global__ void k_zero2(float4* __restrict__ a, int na, float4* __restrict__ b, int nb) {
  float4 z = {0.f, 0.f, 0.f, 0.f};
  for (int i = blockIdx.x * blockDim.x + threadIdx.x; i < na; i += gridDim.x * blockDim.x)
    a[i] = z;
  for (int i = blockIdx.x * blockDim.x + threadIdx.x; i < nb; i += gridDim.x * blockDim.x)
    b[i] = z;
}

__global__ void k_init_v(float* __restrict__ v) {
  int i = blockIdx.x * blockDim.x + threadIdx.x;
  if (i < KB) v[i] = 1.f;
}

// ---------------- power iteration (proven r3) ----------------
template <int MODE>
__global__ __launch_bounds__(256) void k_power_matvec(const float* __restrict__ G,
                                                      const float* __restrict__ vin,
                                                      float* __restrict__ wout,
                                                      float* __restrict__ partial) {
  int rloc = threadIdx.x >> 3;
  int seg = threadIdx.x & 7;
  int row = blockIdx.x * 32 + rloc;
  const float* g = G + (size_t)row * KB + seg * 256;
  const float* vv = vin + seg * 256;
  float s = 0.f;
#pragma unroll 8
  for (int j = 0; j < 256; j += 4) {
    float4 gg = *(const float4*)(g + j);
    float4 vx = *(const float4*)(vv + j);
    s = fmaf(gg.x, vx.x, fmaf(gg.y, vx.y, fmaf(gg.z, vx.z, fmaf(gg.w, vx.w, s))));
  }
#pragma unroll
  for (int off = 1; off < 8; off <<= 1) s += __shfl_xor(s, off, 64);
  if (seg == 0) wout[row] = s;
  float val = (seg == 0) ? (MODE ? vin[row] * s : s * s) : 0.f;
#pragma unroll
  for (int off = 8; off < 64; off <<= 1) val += __shfl_xor(val, off, 64);
  __shared__ float red[4];
  int lane = threadIdx.x & 63, wid = threadIdx.x >> 6;
  if (lane == 0) red[wid] = val;
  __syncthreads();
  if (threadIdx.x == 0) partial[blockIdx.x] = red[0] + red[1] + red[2] + red[3];
}

__global__ void k_power_scale(const float* __restrict__ w, float* __restrict__ v,
                              const float* __restrict__ partial) {
  float n2 = 0.f;
#pragma unroll
  for (int i = 0; i < 64; ++i) n2 += partial[i];
  int i = blockIdx.x * 256 + threadIdx.x;
  v[i] = w[i] / sqrtf(n2);
}

__global__ void k_compute_step(const float* __restrict__ partialL, float* __restrict__ stepbuf) {
  float L = 0.f;
#pragma unroll
  for (int i = 0; i < 64; ++i) L += partialL[i];
  stepbuf[0] = 1.f / L;
}

// ---------------- Cx = x @ phi^T (split-bf16 MFMA, bf16-pair out) ----------------
__global__ __launch_bounds__(256) void k_xphiT(
    const u16* __restrict__ Ah, const u16* __restrict__ Al,
    const u16* __restrict__ Bh, const u16* __restrict__ Bl,
    u16* __restrict__ outH, u16* __restrict__ outL, int N, int K) {
  __shared__ u16 lds[4 * 128 * 32];
  const int tid = threadIdx.x;
  const int w = tid >> 6, l = tid & 63;
  const int row0 = blockIdx.y * 128, col0 = blockIdx.x * 128;
  const int wm = (w >> 1) * 64, wn = (w & 1) * 64;
  const int lrow = l & 15, lk = (l >> 4) * 8;

  f32x4 zero4 = {0.f, 0.f, 0.f, 0.f};
  f32x4 acc[4][4];
#pragma unroll
  for (int i = 0; i < 4; ++i)
#pragma unroll
    for (int j = 0; j < 4; ++j) acc[i][j] = zero4;

  for (int k0 = 0; k0 < K; k0 += 32) {
    {
      const u16* gs[4] = {Ah, Al, Bh, Bl};
      const int r0s[4] = {row0, row0, col0, col0};
#pragma unroll
      for (int st = 0; st < 4; ++st) {
        u16* s = lds + st * 4096;
#pragma unroll
        for (int h = 0; h < 2; ++h) {
          int ch = h * 256 + w * 64 + l;
          const u16* gp = gs[st] + (size_t)(r0s[st] + (ch >> 2)) * K + k0 + (ch & 3) * 8;
          u16* sp = s + (h * 256 + w * 64) * 8;
          __builtin_amdgcn_global_load_lds((const __attribute__((address_space(1))) void*)gp,
                                           (__attribute__((address_space(3))) void*)sp, 16, 0, 0);
        }
      }
    }
    __syncthreads();
    short8 ah[4], al[4];
#pragma unroll
    for (int i = 0; i < 4; ++i) {
      int r = wm + i * 16 + lrow;
      ah[i] = *(const short8*)&lds[0 * 4096 + r * 32 + lk];
      al[i] = *(const short8*)&lds[1 * 4096 + r * 32 + lk];
    }
#pragma unroll
    for (int j = 0; j < 4; ++j) {
      int r = wn + j * 16 + lrow;
      short8 bh = *(const short8*)&lds[2 * 4096 + r * 32 + lk];
      short8 bl = *(const short8*)&lds[3 * 4096 + r * 32 + lk];
#pragma unroll
      for (int i = 0; i < 4; ++i) {
        acc[i][j] = __builtin_amdgcn_mfma_f32_16x16x32_bf16(ah[i], bh, acc[i][j], 0, 0, 0);
        acc[i][j] = __builtin_amdgcn_mfma_f32_16x16x32_bf16(ah[i], bl, acc[i][j], 0, 0, 0);
        acc[i][j] = __builtin_amdgcn_mfma_f32_16x16x32_bf16(al[i], bh, acc[i][j], 0, 0, 0);
      }
    }
    __syncthreads();
  }
#pragma unroll
  for (int i = 0; i < 4; ++i)
#pragma unroll
    for (int r = 0; r < 4; ++r) {
      int m = row0 + wm + i * 16 + ((l >> 4) << 2) + r;
      size_t base = (size_t)m * N;
#pragma unroll
      for (int j = 0; j < 4; ++j) {
        int n = col0 + wn + j * 16 + (l & 15);
        float v = acc[i][j][r];
        u16 hh = f2bf(v);
        outH[base + n] = hh;
        outL[base + n] = f2bf(v - bf2f(hh));
      }
    }
}

// ---------------- fp32 GEMMs (one-time: Gram, recon; proven r3) ----------------
#define BM 128
#define BN 128
#define BKK 16

__global__ __launch_bounds__(256) void k_gram_f32(const float* __restrict__ A,
                                                  const float* __restrict__ Bt,
                                                  float* __restrict__ C, int M, int N, int Kd) {
  __shared__ float As[BKK][BM + 4];
  __shared__ float Bs[BKK][BN + 4];
  int tx = threadIdx.x & 15, ty = threadIdx.x >> 4;
  int row0 = blockIdx.y * BM, col0 = blockIdx.x * BN;
  float acc[8][8] = {};
  for (int k0 = 0; k0 < Kd; k0 += BKK) {
#pragma unroll
    for (int i = 0; i < 2; ++i) {
      int f = threadIdx.x + 256 * i;
      int r = f >> 2, kk = (f & 3) << 2;
      float4 a = *(const float4*)&A[(size_t)(row0 + r) * Kd + k0 + kk];
      As[kk + 0][r] = a.x; As[kk + 1][r] = a.y; As[kk + 2][r] = a.z; As[kk + 3][r] = a.w;
      float4 b = *(const float4*)&Bt[(size_t)(col0 + r) * Kd + k0 + kk];
      Bs[kk + 0][r] = b.x; Bs[kk + 1][r] = b.y; Bs[kk + 2][r] = b.z; Bs[kk + 3][r] = b.w;
    }
    __syncthreads();
#pragma unroll
    for (int k = 0; k < BKK; ++k) {
      float a[8], b[8];
      *(float4*)&a[0] = *(const float4*)&As[k][ty * 8];
      *(float4*)&a[4] = *(const float4*)&As[k][ty * 8 + 4];
      *(float4*)&b[0] = *(const float4*)&Bs[k][tx * 8];
      *(float4*)&b[4] = *(const float4*)&Bs[k][tx * 8 + 4];
#pragma unroll
      for (int i = 0; i < 8; ++i)
#pragma unroll
        for (int j = 0; j < 8; ++j) acc[i][j] = fmaf(a[i], b[j], acc[i][j]);
    }
    __syncthreads();
  }
  int m0 = row0 + ty * 8, n0 = col0 + tx * 8;
#pragma unroll
  for (int i = 0; i < 8; ++i)
#pragma unroll
    for (int j4 = 0; j4 < 2; ++j4) {
      float4 c;
      c.x = acc[i][j4 * 4 + 0]; c.y = acc[i][j4 * 4 + 1];
      c.z = acc[i][j4 * 4 + 2]; c.w = acc[i][j4 * 4 + 3];
      *(float4*)&C[(size_t)(m0 + i) * N + n0 + j4 * 4] = c;
    }
}

__global__ __launch_bounds__(256) void k_recon_f32(const float* __restrict__ A,
                                                   const float* __restrict__ Bm,
                                                   float* __restrict__ C, int M, int N, int Kd) {
  __shared__ float As[BKK][BM + 4];
  __shared__ float Bs[BKK][BN + 4];
  int tx = threadIdx.x & 15, ty = threadIdx.x >> 4;
  int row0 = blockIdx.y * BM, col0 = blockIdx.x * BN;
  float acc[8][8] = {};
  for (int k0 = 0; k0 < Kd; k0 += BKK) {
#pragma unroll
    for (int i = 0; i < 2; ++i) {
      int f = threadIdx.x + 256 * i;
      int r = f >> 2, kk = (f & 3) << 2;
      float4 a = *(const float4*)&A[(size_t)(row0 + r) * Kd + k0 + kk];
      As[kk + 0][r] = a.x; As[kk + 1][r] = a.y; As[kk + 2][r] = a.z; As[kk + 3][r] = a.w;
      int kr = f >> 5, nc = (f & 31) << 2;
      *(float4*)&Bs[kr][nc] = *(const float4*)&Bm[(size_t)(k0 + kr) * N + col0 + nc];
    }
    __syncthreads();
#pragma unroll
    for (int k = 0; k < BKK; ++k) {
      float a[8], b[8];
      *(float4*)&a[0] = *(const float4*)&As[k][ty * 8];
      *(float4*)&a[4] = *(const float4*)&As[k][ty * 8 + 4];
      *(float4*)&b[0] = *(const float4*)&Bs[k][tx * 8];
      *(float4*)&b[4] = *(const float4*)&Bs[k][tx * 8 + 4];
#pragma unroll
      for (int i = 0; i < 8; ++i)
#pragma unroll
        for (int j = 0; j < 8; ++j) acc[i][j] = fmaf(a[i], b[j], acc[i][j]);
    }
    __syncthreads();
  }
  int m0 = row0 + ty * 8, n0 = col0 + tx * 8;
#pragma unroll
  for (int i = 0; i < 8; ++i)
#pragma unroll
    for (int j4 = 0; j4 < 2; ++j4) {
      float4 c;
      c.x = acc[i][j4 * 4 + 0]; c.y = acc[i][j4 * 4 + 1];
      c.z = acc[i][j4 * 4 + 2]; c.w = acc[i][j4 * 4 + 3];
      *(float4*)&C[(size_t)(m0 + i) * N + n0 + j4 * 4] = c;
    }
}

// ---------------- fused FISTA iteration (cooperative) ----------------
// acc = y @ G  over logical K' = 6144 (segments: yh*Gh | yl*Gh | yh*Gl),
// grid.sync, then in-place FISTA update of (Alpha, Yh, Yl).
// 256x256 tile, BK=64, 8 waves (2Mx4N), double-buffered 128KB static LDS.
//
// r10 post-mortem: extra per-phase barriers REGRESSED (29.7ms) - at 1
// block/CU every barrier is a full-CU stall. This round: FEWER barriers
// than r9: 1-tile-ahead prefetch into the OPPOSITE buffer makes the
// exit-barrier provably redundant (buf[p^1]'s old contents were consumed
// before any wave passed the entry barrier). Staging issues FIRST, so
// loads fly under the whole tile's compute (~2300cyc >> 900cyc HBM).
// Sequence/tile: vmcnt(0)[cheap]; s_barrier; stage t+1 -> buf[p^1];
// 24 ds_read + 64 MFMA (setprio-wrapped). T1 remap + T2 swizzle kept.

__device__ __forceinline__ void stage_op(const u16* src, int r0, int q0,
                                         u16* ldsbase, int tid) {
#pragma unroll
  for (int i = 0; i < 4; ++i) {
    int c = i * 512 + tid;
    int r = c >> 3;
    int sp = (c & 7) ^ (r & 7);
    const u16* gp = src + ((size_t)(r0 + r) << 11) + (q0 + (sp << 3));
    u16* lp = ldsbase + ((i * 512 + (tid & 448)) << 3);  // wave-uniform base
    __builtin_amdgcn_global_load_lds((const __attribute__((address_space(1))) void*)gp,
                                     (__attribute__((address_space(3))) void*)lp, 16, 0, 0);
  }
}

__global__ __launch_bounds__(512, 1) void k_fista_fused(
    u16* Yh, u16* Yl,
    const u16* __restrict__ Gh, const u16* __restrict__ Gl,
    const u16* __restrict__ Cxh, const u16* __restrict__ Cxl, float* Alpha,
    const float* __restrict__ stepbuf, float mu) {
  __shared__ u16 lds[65536];  // 128 KB static: [buf][A 16384 u16 | B 16384 u16]

  const int tid = threadIdx.x;
  const int w = tid >> 6, l = tid & 63;
  const int wm = w >> 2, wn = w & 3;       // 2 x 4 waves
  const int lr = l & 15, lg = l >> 4;

  // XCD-aware remap (r9-verified: FETCH 595->332 MB/iter).
  const int lin = blockIdx.x + (int)gridDim.x * blockIdx.y;  // [0,256)
  const int bq = lin >> 6;          // [0,4)
  const int bp = (lin >> 3) & 7;    // [0,8)
  const int br = lin & 7;           // [0,8)
  const int row0 = ((bq << 3) + br) * 256;  // by = 8q + r
  const int col0 = bp * 256;                // bx = p

  f32x4 acc[8][4];
  f32x4 zero4 = {0.f, 0.f, 0.f, 0.f};
#pragma unroll
  for (int i = 0; i < 8; ++i)
#pragma unroll
    for (int j = 0; j < 4; ++j) acc[i][j] = zero4;

  // prologue: stage tile 0 into buf0 only (1-tile-ahead scheme)
  stage_op(Yh, row0, 0, lds, tid);
  stage_op(Gh, col0, 0, lds + 16384, tid);

#define FBODY(TT, B)                                                              \
  {                                                                               \
    asm volatile("s_waitcnt vmcnt(0)" ::: "memory");                              \
    __builtin_amdgcn_s_barrier();                                                 \
    __builtin_amdgcn_sched_barrier(0);                                            \
    {                                                                             \
      int tn = (TT) + 1;                                                          \
      if (tn >= NTILES) tn = 0;                                                   \
      int k0n = tn << 6;                                                          \
      int sg = k0n >> 11;                                                         \
      int q0 = k0n & 2047;                                                        \
      stage_op(sg == 1 ? Yl : Yh, row0, q0, lds + ((B) ? 0 : 32768), tid);        \
      stage_op(sg == 2 ? Gl : Gh, col0, q0, lds + ((B) ? 0 : 32768) + 16384, tid);\
    }                                                                             \
    __builtin_amdgcn_sched_barrier(0);                                            \
    const u16* baseA = lds + ((B) ? 32768 : 0);                                   \
    const u16* baseB = baseA + 16384;                                             \
    short8 bf[4][2];                                                              \
    _Pragma("unroll") for (int j = 0; j < 4; ++j) {                               \
      _Pragma("unroll") for (int ks = 0; ks < 2; ++ks) {                          \
        int brow = wn * 64 + j * 16 + lr;                                         \
        int slot = ks * 4 + lg;                                                   \
        bf[j][ks] = *(const short8*)(baseB + brow * 64 + ((slot ^ (brow & 7)) << 3)); \
      }                                                                           \
    }                                                                             \
    __builtin_amdgcn_s_setprio(1);                                                \
    _Pragma("unroll") for (int i = 0; i < 8; ++i) {                               \
      int arow = wm * 128 + i * 16 + lr;                                          \
      short8 a0 = *(const short8*)(baseA + arow * 64 + (((0 + lg) ^ (arow & 7)) << 3)); \
      short8 a1 = *(const short8*)(baseA + arow * 64 + (((4 + lg) ^ (arow & 7)) << 3)); \
      _Pragma("unroll") for (int j = 0; j < 4; ++j) {                             \
        acc[i][j] = __builtin_amdgcn_mfma_f32_16x16x32_bf16(a0, bf[j][0], acc[i][j], 0, 0, 0); \
        acc[i][j] = __builtin_amdgcn_mfma_f32_16x16x32_bf16(a1, bf[j][1], acc[i][j], 0, 0, 0); \
      }                                                                           \
    }                                                                             \
    __builtin_amdgcn_s_setprio(0);                                                \
  }

  for (int tt = 0; tt < NTILES; tt += 2) {
    FBODY(tt, 0)
    FBODY(tt + 1, 1)
  }
#undef FBODY

  asm volatile("s_waitcnt vmcnt(0)" ::: "memory");
  cg::this_grid().sync();

  // ---- fused FISTA epilogue: each block updates only its own C-tile ----
  const float step = stepbuf[0];
  const float thr = LAM * step;
#pragma unroll
  for (int i = 0; i < 8; ++i) {
#pragma unroll
    for (int r = 0; r < 4; ++r) {
      int m = row0 + wm * 128 + i * 16 + (lg << 2) + r;
      size_t base = (size_t)m * KB;
#pragma unroll
      for (int j = 0; j < 4; ++j) {
        int n = col0 + wn * 64 + j * 16 + lr;
        size_t idx = base + n;
        float g = acc[i][j][r] - (bf2f(Cxh[idx]) + bf2f(Cxl[idx]));
        float y = bf2f(Yh[idx]) + bf2f(Yl[idx]);
        float z = y - step * g;
        float az = fabsf(z) - thr;
        float a = az > 0.f ? copysignf(az, z) : 0.f;
        float ap = Alpha[idx];
        float yn = a + mu * (a - ap);
        Alpha[idx] = a;
        u16 hh = f2bf(yn);
        Yh[idx] = hh;
        Yl[idx] = f2bf(yn - bf2f(hh));
      }
    }
  }
}

// ---------------- launch ----------------
extern "C" void kernel_launch(void* const* d_in, const int* in_sizes, int n_in,
                              void* d_out, int out_size, void* d_ws, size_t ws_size,
                              hipStream_t stream) {
  const float* x = (const float*)d_in[0];    // [8192,1024]
  const float* phi = (const float*)d_in[1];  // [2048,1024]
  float* out = (float*)d_out;
  float* alpha = out;                             // [8192*2048] fp32, in-place FISTA state
  float* reconF = out + (size_t)BATCH * KB;       // [8192*1024] fp32 (33.55 MB scratch region)

  // ---- workspace layout (byte offsets) ----
  char* ws = (char*)d_ws;
  u16* Yh = (u16*)ws;                                   // 33,554,432 B
  u16* Yl = (u16*)(ws + 33554432ull);                   // 33,554,432 B
  u16* Gph = (u16*)(ws + 67108864ull);                  // 8,388,608 B  (G' hi; temp phiH)
  u16* Gpl = (u16*)(ws + 75497472ull);                  // 8,388,608 B  (G' lo; temp phiL)
  u16* Cxh = (u16*)(ws + 83886080ull);                  // 33,554,432 B
  u16* Cxl = (u16*)(ws + 117440512ull);                 // 33,554,432 B
  float* stepbuf = (float*)(ws + 150994944ull);         // 64 B
  const size_t need = 150995008ull;
  if (ws_size < need) return;

  // pre-FISTA temporaries:
  float* Gf = (float*)Yh;           // G fp32 [2048][2048] = 16.78 MB in Yh/Yl region
  u16* xh = (u16*)reconF;           // x split hi [8192*1024]
  u16* xl = xh + (size_t)BATCH * DD;
  float* vbuf = reconF;             // power-iter scratch (after Cx done, xh/xl dead)
  float* wbuf = reconF + 2048;
  float* normPart = reconF + 4096;  // 50*64
  float* LPart = reconF + 7296;     // 64

  // 1. splits: phi -> (Gph,Gpl temp), x -> (xh,xl in recon region)
  k_split_f32<<<2048, 256, 0, stream>>>(phi, Gph, Gpl, KB * DD);
  k_split_f32<<<2048, 256, 0, stream>>>(x, xh, xl, BATCH * DD);

  // 2. Cx = x @ phi^T (bf16-pair out), M=8192 N=2048 K=1024
  k_xphiT<<<dim3(KB / 128, BATCH / 128), 256, 0, stream>>>(xh, xl, Gph, Gpl, Cxh, Cxl, KB, DD);

  // 3. G = phi @ phi^T (fp32) into Yh region
  k_gram_f32<<<dim3(KB / BN, KB / BM), 256, 0, stream>>>(phi, phi, Gf, KB, KB, DD);

  // 4. power iteration -> step = 1/L  (scratch in recon region; xh/xl dead)
  k_init_v<<<8, 256, 0, stream>>>(vbuf);
  for (int s = 0; s < N_POWER; ++s) {
    k_power_matvec<0><<<64, 256, 0, stream>>>(Gf, vbuf, wbuf, normPart + s * 64);
    k_power_scale<<<KB / 256, 256, 0, stream>>>(wbuf, vbuf, normPart + s * 64);
  }
  k_power_matvec<1><<<64, 256, 0, stream>>>(Gf, vbuf, wbuf, LPart);
  k_compute_step<<<1, 1, 0, stream>>>(LPart, stepbuf);

  // 5. G' = split(G) (overwrites phi splits; they are dead)
  k_split_f32<<<2048, 256, 0, stream>>>(Gf, Gph, Gpl, KB * KB);

  // 6. zero Y (kills G) and alpha
  k_zero2<<<2048, 256, 0, stream>>>((float4*)Yh, (int)(67108864 / 16),
                                    (float4*)alpha, (int)(67108864 / 16));

  // 7. FISTA: 100 cooperative fused iterations
  float t = 1.f;
  float mus[N_ITER];
  for (int it = 0; it < N_ITER; ++it) {
    float tn = 0.5f * (1.f + sqrtf(1.f + 4.f * t * t));
    mus[it] = (t - 1.f) / tn;
    t = tn;
  }
  u16 *pYh = Yh, *pYl = Yl;
  const u16 *pGh = Gph, *pGl = Gpl;
  const u16 *pCxh = Cxh, *pCxl = Cxl;
  float* pAl = alpha;
  const float* pStep = stepbuf;
  for (int it = 0; it < N_ITER; ++it) {
    void* kargs[9] = {&pYh, &pYl, &pGh, &pGl, &pCxh, &pCxl, &pAl, &pStep, &mus[it]};
    (void)hipLaunchCooperativeKernel((const void*)k_fista_fused, dim3(KB / 256, BATCH / 256),
                                     dim3(512), kargs, 0, stream);
  }

  // 8. recon = alpha @ phi (fp32; overwrites recon-region scratch)
  k_recon_f32<<<dim3(DD / BN, BATCH / BM), 256, 0, stream>>>(
      alpha, phi, reconF, BATCH, DD, KB);
}

// Round 12
// 21294.894 us; speedup vs baseline: 1.3943x; 1.2284x over previous
//
#include <hip/hip_runtime.h>
#include <hip/hip_cooperative_groups.h>
#include <math.h>

namespace cg = cooperative_groups;

#define BATCH 8192
#define KB 2048      // num basis (N of fused GEMM)
#define DD 1024      // dim basis
#define LAM 0.1f
#define N_ITER 100
#define N_POWER 50
#define NTILES 64    // K' = 4096 = 64 * 64  (fp16 2-term: yh|yl vs Gh)

typedef unsigned short u16;
using short8 = __attribute__((ext_vector_type(8))) short;
using f32x4  = __attribute__((ext_vector_type(4))) float;

// ---------- bf16 split helpers (RNE) ----------
__device__ __forceinline__ u16 f2bf(float f) {
  unsigned int u = __builtin_bit_cast(unsigned int, f);
  u = u + 0x7FFFu + ((u >> 16) & 1u);
  return (u16)(u >> 16);
}
__device__ __forceinline__ float bf2f(u16 s) {
  unsigned int u = ((unsigned int)s) << 16;
  return __builtin_bit_cast(float, u);
}

// ---------- fp16 split helpers (RNE via HW cvt) ----------
__device__ __forceinline__ u16 f2h(float f) {
  _Float16 h = (_Float16)f;
  return __builtin_bit_cast(unsigned short, h);
}
__device__ __forceinline__ float h2f(u16 s) {
  _Float16 h = __builtin_bit_cast(_Float16, s);
  return (float)h;
}

// ---------------- utility kernels ----------------
__global__ void k_split_f32(const float* __restrict__ in, u16* __restrict__ h,
                            u16* __restrict__ lo, int n) {  // bf16 pair
  for (int i = blockIdx.x * blockDim.x + threadIdx.x; i < n; i += gridDim.x * blockDim.x) {
    float v = in[i];
    u16 hh = f2bf(v);
    h[i] = hh;
    lo[i] = f2bf(v - bf2f(hh));
  }
}

__global__ void k_cvt_f16(const float* __restrict__ in, u16* __restrict__ h, int n) {
  for (int i = blockIdx.x * blockDim.x + threadIdx.x; i < n; i += gridDim.x * blockDim.x)
    h[i] = f2h(in[i]);
}

__global__ void k_zero2(float4* __restrict__ a, int na, float4* __restrict__ b, int nb) {
  float4 z = {0.f, 0.f, 0.f, 0.f};
  for (int i = blockIdx.x * blockDim.x + threadIdx.x; i < na; i += gridDim.x * blockDim.x)
    a[i] = z;
  for (int i = blockIdx.x * blockDim.x + threadIdx.x; i < nb; i += gridDim.x * blockDim.x)
    b[i] = z;
}

__global__ void k_init_v(float* __restrict__ v) {
  int i = blockIdx.x * blockDim.x + threadIdx.x;
  if (i < KB) v[i] = 1.f;
}

// ---------------- power iteration (proven r3) ----------------
template <int MODE>
__global__ __launch_bounds__(256) void k_power_matvec(const float* __restrict__ G,
                                                      const float* __restrict__ vin,
                                                      float* __restrict__ wout,
                                                      float* __restrict__ partial) {
  int rloc = threadIdx.x >> 3;
  int seg = threadIdx.x & 7;
  int row = blockIdx.x * 32 + rloc;
  const float* g = G + (size_t)row * KB + seg * 256;
  const float* vv = vin + seg * 256;
  float s = 0.f;
#pragma unroll 8
  for (int j = 0; j < 256; j += 4) {
    float4 gg = *(const float4*)(g + j);
    float4 vx = *(const float4*)(vv + j);
    s = fmaf(gg.x, vx.x, fmaf(gg.y, vx.y, fmaf(gg.z, vx.z, fmaf(gg.w, vx.w, s))));
  }
#pragma unroll
  for (int off = 1; off < 8; off <<= 1) s += __shfl_xor(s, off, 64);
  if (seg == 0) wout[row] = s;
  float val = (seg == 0) ? (MODE ? vin[row] * s : s * s) : 0.f;
#pragma unroll
  for (int off = 8; off < 64; off <<= 1) val += __shfl_xor(val, off, 64);
  __shared__ float red[4];
  int lane = threadIdx.x & 63, wid = threadIdx.x >> 6;
  if (lane == 0) red[wid] = val;
  __syncthreads();
  if (threadIdx.x == 0) partial[blockIdx.x] = red[0] + red[1] + red[2] + red[3];
}

__global__ void k_power_scale(const float* __restrict__ w, float* __restrict__ v,
                              const float* __restrict__ partial) {
  float n2 = 0.f;
#pragma unroll
  for (int i = 0; i < 64; ++i) n2 += partial[i];
  int i = blockIdx.x * 256 + threadIdx.x;
  v[i] = w[i] / sqrtf(n2);
}

__global__ void k_compute_step(const float* __restrict__ partialL, float* __restrict__ stepbuf) {
  float L = 0.f;
#pragma unroll
  for (int i = 0; i < 64; ++i) L += partialL[i];
  stepbuf[0] = 1.f / L;
}

// ---------------- Cx = x @ phi^T (split-bf16 MFMA, bf16-pair out; r3-proven) ----------------
__global__ __launch_bounds__(256) void k_xphiT(
    const u16* __restrict__ Ah, const u16* __restrict__ Al,
    const u16* __restrict__ Bh, const u16* __restrict__ Bl,
    u16* __restrict__ outH, u16* __restrict__ outL, int N, int K) {
  __shared__ u16 lds[4 * 128 * 32];
  const int tid = threadIdx.x;
  const int w = tid >> 6, l = tid & 63;
  const int row0 = blockIdx.y * 128, col0 = blockIdx.x * 128;
  const int wm = (w >> 1) * 64, wn = (w & 1) * 64;
  const int lrow = l & 15, lk = (l >> 4) * 8;

  f32x4 zero4 = {0.f, 0.f, 0.f, 0.f};
  f32x4 acc[4][4];
#pragma unroll
  for (int i = 0; i < 4; ++i)
#pragma unroll
    for (int j = 0; j < 4; ++j) acc[i][j] = zero4;

  for (int k0 = 0; k0 < K; k0 += 32) {
    {
      const u16* gs[4] = {Ah, Al, Bh, Bl};
      const int r0s[4] = {row0, row0, col0, col0};
#pragma unroll
      for (int st = 0; st < 4; ++st) {
        u16* s = lds + st * 4096;
#pragma unroll
        for (int h = 0; h < 2; ++h) {
          int ch = h * 256 + w * 64 + l;
          const u16* gp = gs[st] + (size_t)(r0s[st] + (ch >> 2)) * K + k0 + (ch & 3) * 8;
          u16* sp = s + (h * 256 + w * 64) * 8;
          __builtin_amdgcn_global_load_lds((const __attribute__((address_space(1))) void*)gp,
                                           (__attribute__((address_space(3))) void*)sp, 16, 0, 0);
        }
      }
    }
    __syncthreads();
    short8 ah[4], al[4];
#pragma unroll
    for (int i = 0; i < 4; ++i) {
      int r = wm + i * 16 + lrow;
      ah[i] = *(const short8*)&lds[0 * 4096 + r * 32 + lk];
      al[i] = *(const short8*)&lds[1 * 4096 + r * 32 + lk];
    }
#pragma unroll
    for (int j = 0; j < 4; ++j) {
      int r = wn + j * 16 + lrow;
      short8 bh = *(const short8*)&lds[2 * 4096 + r * 32 + lk];
      short8 bl = *(const short8*)&lds[3 * 4096 + r * 32 + lk];
#pragma unroll
      for (int i = 0; i < 4; ++i) {
        acc[i][j] = __builtin_amdgcn_mfma_f32_16x16x32_bf16(ah[i], bh, acc[i][j], 0, 0, 0);
        acc[i][j] = __builtin_amdgcn_mfma_f32_16x16x32_bf16(ah[i], bl, acc[i][j], 0, 0, 0);
        acc[i][j] = __builtin_amdgcn_mfma_f32_16x16x32_bf16(al[i], bh, acc[i][j], 0, 0, 0);
      }
    }
    __syncthreads();
  }
#pragma unroll
  for (int i = 0; i < 4; ++i)
#pragma unroll
    for (int r = 0; r < 4; ++r) {
      int m = row0 + wm + i * 16 + ((l >> 4) << 2) + r;
      size_t base = (size_t)m * N;
#pragma unroll
      for (int j = 0; j < 4; ++j) {
        int n = col0 + wn + j * 16 + (l & 15);
        float v = acc[i][j][r];
        u16 hh = f2bf(v);
        outH[base + n] = hh;
        outL[base + n] = f2bf(v - bf2f(hh));
      }
    }
}

// ---------------- fp32 GEMMs (one-time: Gram, recon; proven r3) ----------------
#define BM 128
#define BN 128
#define BKK 16

__global__ __launch_bounds__(256) void k_gram_f32(const float* __restrict__ A,
                                                  const float* __restrict__ Bt,
                                                  float* __restrict__ C, int M, int N, int Kd) {
  __shared__ float As[BKK][BM + 4];
  __shared__ float Bs[BKK][BN + 4];
  int tx = threadIdx.x & 15, ty = threadIdx.x >> 4;
  int row0 = blockIdx.y * BM, col0 = blockIdx.x * BN;
  float acc[8][8] = {};
  for (int k0 = 0; k0 < Kd; k0 += BKK) {
#pragma unroll
    for (int i = 0; i < 2; ++i) {
      int f = threadIdx.x + 256 * i;
      int r = f >> 2, kk = (f & 3) << 2;
      float4 a = *(const float4*)&A[(size_t)(row0 + r) * Kd + k0 + kk];
      As[kk + 0][r] = a.x; As[kk + 1][r] = a.y; As[kk + 2][r] = a.z; As[kk + 3][r] = a.w;
      float4 b = *(const float4*)&Bt[(size_t)(col0 + r) * Kd + k0 + kk];
      Bs[kk + 0][r] = b.x; Bs[kk + 1][r] = b.y; Bs[kk + 2][r] = b.z; Bs[kk + 3][r] = b.w;
    }
    __syncthreads();
#pragma unroll
    for (int k = 0; k < BKK; ++k) {
      float a[8], b[8];
      *(float4*)&a[0] = *(const float4*)&As[k][ty * 8];
      *(float4*)&a[4] = *(const float4*)&As[k][ty * 8 + 4];
      *(float4*)&b[0] = *(const float4*)&Bs[k][tx * 8];
      *(float4*)&b[4] = *(const float4*)&Bs[k][tx * 8 + 4];
#pragma unroll
      for (int i = 0; i < 8; ++i)
#pragma unroll
        for (int j = 0; j < 8; ++j) acc[i][j] = fmaf(a[i], b[j], acc[i][j]);
    }
    __syncthreads();
  }
  int m0 = row0 + ty * 8, n0 = col0 + tx * 8;
#pragma unroll
  for (int i = 0; i < 8; ++i)
#pragma unroll
    for (int j4 = 0; j4 < 2; ++j4) {
      float4 c;
      c.x = acc[i][j4 * 4 + 0]; c.y = acc[i][j4 * 4 + 1];
      c.z = acc[i][j4 * 4 + 2]; c.w = acc[i][j4 * 4 + 3];
      *(float4*)&C[(size_t)(m0 + i) * N + n0 + j4 * 4] = c;
    }
}

__global__ __launch_bounds__(256) void k_recon_f32(const float* __restrict__ A,
                                                   const float* __restrict__ Bm,
                                                   float* __restrict__ C, int M, int N, int Kd) {
  __shared__ float As[BKK][BM + 4];
  __shared__ float Bs[BKK][BN + 4];
  int tx = threadIdx.x & 15, ty = threadIdx.x >> 4;
  int row0 = blockIdx.y * BM, col0 = blockIdx.x * BN;
  float acc[8][8] = {};
  for (int k0 = 0; k0 < Kd; k0 += BKK) {
#pragma unroll
    for (int i = 0; i < 2; ++i) {
      int f = threadIdx.x + 256 * i;
      int r = f >> 2, kk = (f & 3) << 2;
      float4 a = *(const float4*)&A[(size_t)(row0 + r) * Kd + k0 + kk];
      As[kk + 0][r] = a.x; As[kk + 1][r] = a.y; As[kk + 2][r] = a.z; As[kk + 3][r] = a.w;
      int kr = f >> 5, nc = (f & 31) << 2;
      *(float4*)&Bs[kr][nc] = *(const float4*)&Bm[(size_t)(k0 + kr) * N + col0 + nc];
    }
    __syncthreads();
#pragma unroll
    for (int k = 0; k < BKK; ++k) {
      float a[8], b[8];
      *(float4*)&a[0] = *(const float4*)&As[k][ty * 8];
      *(float4*)&a[4] = *(const float4*)&As[k][ty * 8 + 4];
      *(float4*)&b[0] = *(const float4*)&Bs[k][tx * 8];
      *(float4*)&b[4] = *(const float4*)&Bs[k][tx * 8 + 4];
#pragma unroll
      for (int i = 0; i < 8; ++i)
#pragma unroll
        for (int j = 0; j < 8; ++j) acc[i][j] = fmaf(a[i], b[j], acc[i][j]);
    }
    __syncthreads();
  }
  int m0 = row0 + ty * 8, n0 = col0 + tx * 8;
#pragma unroll
  for (int i = 0; i < 8; ++i)
#pragma unroll
    for (int j4 = 0; j4 < 2; ++j4) {
      float4 c;
      c.x = acc[i][j4 * 4 + 0]; c.y = acc[i][j4 * 4 + 1];
      c.z = acc[i][j4 * 4 + 2]; c.w = acc[i][j4 * 4 + 3];
      *(float4*)&C[(size_t)(m0 + i) * N + n0 + j4 * 4] = c;
    }
}

// ---------------- fused FISTA iteration (cooperative) ----------------
// fp16 2-term: acc = (yh + yl) @ Gh over K' = 4096 (segs: yh*Gh | yl*Gh).
// y-side split exact to 2^-22; only error is the FIXED perturbation G->Gh
// (rel ~2^-11) — FISTA converges to the Gh-problem's solution. -33% MFMA,
// LDS reads, B-staging vs bf16 3-term (r11). Structure unchanged from r11:
// 256x256 tile, BK=64, 8 waves, 1 barrier/tile, stage-first 1-tile-ahead
// prefetch into opposite buffer, T1 XCD remap, T2 swizzle, T5 setprio.

__device__ __forceinline__ void stage_op(const u16* src, int r0, int q0,
                                         u16* ldsbase, int tid) {
#pragma unroll
  for (int i = 0; i < 4; ++i) {
    int c = i * 512 + tid;
    int r = c >> 3;
    int sp = (c & 7) ^ (r & 7);
    const u16* gp = src + ((size_t)(r0 + r) << 11) + (q0 + (sp << 3));
    u16* lp = ldsbase + ((i * 512 + (tid & 448)) << 3);  // wave-uniform base
    __builtin_amdgcn_global_load_lds((const __attribute__((address_space(1))) void*)gp,
                                     (__attribute__((address_space(3))) void*)lp, 16, 0, 0);
  }
}

__global__ __launch_bounds__(512, 1) void k_fista_fused(
    u16* Yh, u16* Yl,
    const u16* __restrict__ Gh,
    const u16* __restrict__ Cxh, const u16* __restrict__ Cxl, float* Alpha,
    const float* __restrict__ stepbuf, float mu) {
  __shared__ u16 lds[65536];  // 128 KB static: [buf][A 16384 u16 | B 16384 u16]

  const int tid = threadIdx.x;
  const int w = tid >> 6, l = tid & 63;
  const int wm = w >> 2, wn = w & 3;       // 2 x 4 waves
  const int lr = l & 15, lg = l >> 4;

  // XCD-aware remap (r9-verified: FETCH 595->332 MB/iter).
  const int lin = blockIdx.x + (int)gridDim.x * blockIdx.y;  // [0,256)
  const int bq = lin >> 6;          // [0,4)
  const int bp = (lin >> 3) & 7;    // [0,8)
  const int br = lin & 7;           // [0,8)
  const int row0 = ((bq << 3) + br) * 256;  // by = 8q + r
  const int col0 = bp * 256;                // bx = p

  f32x4 acc[8][4];
  f32x4 zero4 = {0.f, 0.f, 0.f, 0.f};
#pragma unroll
  for (int i = 0; i < 8; ++i)
#pragma unroll
    for (int j = 0; j < 4; ++j) acc[i][j] = zero4;

  // prologue: stage tile 0 into buf0 only (1-tile-ahead scheme)
  stage_op(Yh, row0, 0, lds, tid);
  stage_op(Gh, col0, 0, lds + 16384, tid);

#define FBODY(TT, B)                                                              \
  {                                                                               \
    asm volatile("s_waitcnt vmcnt(0)" ::: "memory");                              \
    __builtin_amdgcn_s_barrier();                                                 \
    __builtin_amdgcn_sched_barrier(0);                                            \
    {                                                                             \
      int tn = (TT) + 1;                                                          \
      if (tn >= NTILES) tn = 0;                                                   \
      int sg = tn >> 5;                                                           \
      int q0 = (tn & 31) << 6;                                                    \
      stage_op(sg ? Yl : Yh, row0, q0, lds + ((B) ? 0 : 32768), tid);             \
      stage_op(Gh, col0, q0, lds + ((B) ? 0 : 32768) + 16384, tid);               \
    }                                                                             \
    __builtin_amdgcn_sched_barrier(0);                                            \
    const u16* baseA = lds + ((B) ? 32768 : 0);                                   \
    const u16* baseB = baseA + 16384;                                             \
    short8 bf[4][2];                                                              \
    _Pragma("unroll") for (int j = 0; j < 4; ++j) {                               \
      _Pragma("unroll") for (int ks = 0; ks < 2; ++ks) {                          \
        int brow = wn * 64 + j * 16 + lr;                                         \
        int slot = ks * 4 + lg;                                                   \
        bf[j][ks] = *(const short8*)(baseB + brow * 64 + ((slot ^ (brow & 7)) << 3)); \
      }                                                                           \
    }                                                                             \
    __builtin_amdgcn_s_setprio(1);                                                \
    _Pragma("unroll") for (int i = 0; i < 8; ++i) {                               \
      int arow = wm * 128 + i * 16 + lr;                                          \
      short8 a0 = *(const short8*)(baseA + arow * 64 + (((0 + lg) ^ (arow & 7)) << 3)); \
      short8 a1 = *(const short8*)(baseA + arow * 64 + (((4 + lg) ^ (arow & 7)) << 3)); \
      _Pragma("unroll") for (int j = 0; j < 4; ++j) {                             \
        acc[i][j] = __builtin_amdgcn_mfma_f32_16x16x32_f16(a0, bf[j][0], acc[i][j], 0, 0, 0); \
        acc[i][j] = __builtin_amdgcn_mfma_f32_16x16x32_f16(a1, bf[j][1], acc[i][j], 0, 0, 0); \
      }                                                                           \
    }                                                                             \
    __builtin_amdgcn_s_setprio(0);                                                \
  }

  for (int tt = 0; tt < NTILES; tt += 2) {
    FBODY(tt, 0)
    FBODY(tt + 1, 1)
  }
#undef FBODY

  asm volatile("s_waitcnt vmcnt(0)" ::: "memory");
  cg::this_grid().sync();

  // ---- fused FISTA epilogue: each block updates only its own C-tile ----
  const float step = stepbuf[0];
  const float thr = LAM * step;
#pragma unroll
  for (int i = 0; i < 8; ++i) {
#pragma unroll
    for (int r = 0; r < 4; ++r) {
      int m = row0 + wm * 128 + i * 16 + (lg << 2) + r;
      size_t base = (size_t)m * KB;
#pragma unroll
      for (int j = 0; j < 4; ++j) {
        int n = col0 + wn * 64 + j * 16 + lr;
        size_t idx = base + n;
        float g = acc[i][j][r] - (bf2f(Cxh[idx]) + bf2f(Cxl[idx]));
        float y = h2f(Yh[idx]) + h2f(Yl[idx]);
        float z = y - step * g;
        float az = fabsf(z) - thr;
        float a = az > 0.f ? copysignf(az, z) : 0.f;
        float ap = Alpha[idx];
        float yn = a + mu * (a - ap);
        Alpha[idx] = a;
        u16 hh = f2h(yn);
        Yh[idx] = hh;
        Yl[idx] = f2h(yn - h2f(hh));
      }
    }
  }
}

// ---------------- launch ----------------
extern "C" void kernel_launch(void* const* d_in, const int* in_sizes, int n_in,
                              void* d_out, int out_size, void* d_ws, size_t ws_size,
                              hipStream_t stream) {
  const float* x = (const float*)d_in[0];    // [8192,1024]
  const float* phi = (const float*)d_in[1];  // [2048,1024]
  float* out = (float*)d_out;
  float* alpha = out;                             // [8192*2048] fp32, in-place FISTA state
  float* reconF = out + (size_t)BATCH * KB;       // [8192*1024] fp32 (33.55 MB scratch region)

  // ---- workspace layout (byte offsets) ----
  char* ws = (char*)d_ws;
  u16* Yh = (u16*)ws;                                   // 33,554,432 B (fp16 hi)
  u16* Yl = (u16*)(ws + 33554432ull);                   // 33,554,432 B (fp16 lo)
  u16* Gph = (u16*)(ws + 67108864ull);                  // 8,388,608 B  (Gh fp16; temp phiH bf16)
  u16* Gpl = (u16*)(ws + 75497472ull);                  // 8,388,608 B  (temp phiL bf16; unused after Cx)
  u16* Cxh = (u16*)(ws + 83886080ull);                  // 33,554,432 B
  u16* Cxl = (u16*)(ws + 117440512ull);                 // 33,554,432 B
  float* stepbuf = (float*)(ws + 150994944ull);         // 64 B
  const size_t need = 150995008ull;
  if (ws_size < need) return;

  // pre-FISTA temporaries:
  float* Gf = (float*)Yh;           // G fp32 [2048][2048] = 16.78 MB in Yh/Yl region
  u16* xh = (u16*)reconF;           // x split hi [8192*1024]
  u16* xl = xh + (size_t)BATCH * DD;
  float* vbuf = reconF;             // power-iter scratch (after Cx done, xh/xl dead)
  float* wbuf = reconF + 2048;
  float* normPart = reconF + 4096;  // 50*64
  float* LPart = reconF + 7296;     // 64

  // 1. splits: phi -> (Gph,Gpl temp, bf16), x -> (xh,xl in recon region)
  k_split_f32<<<2048, 256, 0, stream>>>(phi, Gph, Gpl, KB * DD);
  k_split_f32<<<2048, 256, 0, stream>>>(x, xh, xl, BATCH * DD);

  // 2. Cx = x @ phi^T (bf16-pair out), M=8192 N=2048 K=1024
  k_xphiT<<<dim3(KB / 128, BATCH / 128), 256, 0, stream>>>(xh, xl, Gph, Gpl, Cxh, Cxl, KB, DD);

  // 3. G = phi @ phi^T (fp32) into Yh region
  k_gram_f32<<<dim3(KB / BN, KB / BM), 256, 0, stream>>>(phi, phi, Gf, KB, KB, DD);

  // 4. power iteration -> step = 1/L  (scratch in recon region; xh/xl dead)
  k_init_v<<<8, 256, 0, stream>>>(vbuf);
  for (int s = 0; s < N_POWER; ++s) {
    k_power_matvec<0><<<64, 256, 0, stream>>>(Gf, vbuf, wbuf, normPart + s * 64);
    k_power_scale<<<KB / 256, 256, 0, stream>>>(wbuf, vbuf, normPart + s * 64);
  }
  k_power_matvec<1><<<64, 256, 0, stream>>>(Gf, vbuf, wbuf, LPart);
  k_compute_step<<<1, 1, 0, stream>>>(LPart, stepbuf);

  // 5. Gh = fp16(G) (overwrites phiH split; it is dead after Cx)
  k_cvt_f16<<<2048, 256, 0, stream>>>(Gf, Gph, KB * KB);

  // 6. zero Y (kills G) and alpha
  k_zero2<<<2048, 256, 0, stream>>>((float4*)Yh, (int)(67108864 / 16),
                                    (float4*)alpha, (int)(67108864 / 16));

  // 7. FISTA: 100 cooperative fused iterations
  float t = 1.f;
  float mus[N_ITER];
  for (int it = 0; it < N_ITER; ++it) {
    float tn = 0.5f * (1.f + sqrtf(1.f + 4.f * t * t));
    mus[it] = (t - 1.f) / tn;
    t = tn;
  }
  u16 *pYh = Yh, *pYl = Yl;
  const u16* pGh = Gph;
  const u16 *pCxh = Cxh, *pCxl = Cxl;
  float* pAl = alpha;
  const float* pStep = stepbuf;
  for (int it = 0; it < N_ITER; ++it) {
    void* kargs[8] = {&pYh, &pYl, &pGh, &pCxh, &pCxl, &pAl, &pStep, &mus[it]};
    (void)hipLaunchCooperativeKernel((const void*)k_fista_fused, dim3(KB / 256, BATCH / 256),
                                     dim3(512), kargs, 0, stream);
  }

  // 8. recon = alpha @ phi (fp32; overwrites recon-region scratch)
  k_recon_f32<<<dim3(DD / BN, BATCH / BM), 256, 0, stream>>>(
      alpha, phi, reconF, BATCH, DD, KB);
}

// Round 16
// 14807.906 us; speedup vs baseline: 2.0051x; 1.4381x over previous
//
#include <hip/hip_runtime.h>
#include <hip/hip_cooperative_groups.h>
#include <math.h>

namespace cg = cooperative_groups;

#define BATCH 8192
#define KB 2048      // num basis (N of fused GEMM)
#define DD 1024      // dim basis
#define LAM 0.1f
#define N_ITER 100
#define N_POWER 50
#define NTILES 32    // K' = 2048 = 32 * 64  (fp16 1-term: yh vs Gh)

typedef unsigned short u16;
using short8 = __attribute__((ext_vector_type(8))) short;
using f32x4  = __attribute__((ext_vector_type(4))) float;

// ---------- bf16 split helpers (RNE) ----------
__device__ __forceinline__ u16 f2bf(float f) {
  unsigned int u = __builtin_bit_cast(unsigned int, f);
  u = u + 0x7FFFu + ((u >> 16) & 1u);
  return (u16)(u >> 16);
}
__device__ __forceinline__ float bf2f(u16 s) {
  unsigned int u = ((unsigned int)s) << 16;
  return __builtin_bit_cast(float, u);
}

// ---------- fp16 helpers (RNE via HW cvt) ----------
__device__ __forceinline__ u16 f2h(float f) {
  _Float16 h = (_Float16)f;
  return __builtin_bit_cast(unsigned short, h);
}
__device__ __forceinline__ float h2f(u16 s) {
  _Float16 h = __builtin_bit_cast(_Float16, s);
  return (float)h;
}

// ---------------- utility kernels ----------------
__global__ void k_split_f32(const float* __restrict__ in, u16* __restrict__ h,
                            u16* __restrict__ lo, int n) {  // bf16 pair
  for (int i = blockIdx.x * blockDim.x + threadIdx.x; i < n; i += gridDim.x * blockDim.x) {
    float v = in[i];
    u16 hh = f2bf(v);
    h[i] = hh;
    lo[i] = f2bf(v - bf2f(hh));
  }
}

__global__ void k_cvt_f16(const float* __restrict__ in, u16* __restrict__ h, int n) {
  for (int i = blockIdx.x * blockDim.x + threadIdx.x; i < n; i += gridDim.x * blockDim.x)
    h[i] = f2h(in[i]);
}

__global__ void k_zero2(float4* __restrict__ a, int na, float4* __restrict__ b, int nb) {
  float4 z = {0.f, 0.f, 0.f, 0.f};
  for (int i = blockIdx.x * blockDim.x + threadIdx.x; i < na; i += gridDim.x * blockDim.x)
    a[i] = z;
  for (int i = blockIdx.x * blockDim.x + threadIdx.x; i < nb; i += gridDim.x * blockDim.x)
    b[i] = z;
}

__global__ void k_init_v(float* __restrict__ v) {
  int i = blockIdx.x * blockDim.x + threadIdx.x;
  if (i < KB) v[i] = 1.f;
}

// ---------------- power iteration (proven r3) ----------------
template <int MODE>
__global__ __launch_bounds__(256) void k_power_matvec(const float* __restrict__ G,
                                                      const float* __restrict__ vin,
                                                      float* __restrict__ wout,
                                                      float* __restrict__ partial) {
  int rloc = threadIdx.x >> 3;
  int seg = threadIdx.x & 7;
  int row = blockIdx.x * 32 + rloc;
  const float* g = G + (size_t)row * KB + seg * 256;
  const float* vv = vin + seg * 256;
  float s = 0.f;
#pragma unroll 8
  for (int j = 0; j < 256; j += 4) {
    float4 gg = *(const float4*)(g + j);
    float4 vx = *(const float4*)(vv + j);
    s = fmaf(gg.x, vx.x, fmaf(gg.y, vx.y, fmaf(gg.z, vx.z, fmaf(gg.w, vx.w, s))));
  }
#pragma unroll
  for (int off = 1; off < 8; off <<= 1) s += __shfl_xor(s, off, 64);
  if (seg == 0) wout[row] = s;
  float val = (seg == 0) ? (MODE ? vin[row] * s : s * s) : 0.f;
#pragma unroll
  for (int off = 8; off < 64; off <<= 1) val += __shfl_xor(val, off, 64);
  __shared__ float red[4];
  int lane = threadIdx.x & 63, wid = threadIdx.x >> 6;
  if (lane == 0) red[wid] = val;
  __syncthreads();
  if (threadIdx.x == 0) partial[blockIdx.x] = red[0] + red[1] + red[2] + red[3];
}

__global__ void k_power_scale(const float* __restrict__ w, float* __restrict__ v,
                              const float* __restrict__ partial) {
  float n2 = 0.f;
#pragma unroll
  for (int i = 0; i < 64; ++i) n2 += partial[i];
  int i = blockIdx.x * 256 + threadIdx.x;
  v[i] = w[i] / sqrtf(n2);
}

__global__ void k_compute_step(const float* __restrict__ partialL, float* __restrict__ stepbuf) {
  float L = 0.f;
#pragma unroll
  for (int i = 0; i < 64; ++i) L += partialL[i];
  stepbuf[0] = 1.f / L;
}

// ---------------- Cx = x @ phi^T (split-bf16 MFMA, bf16-pair out; r3-proven) ----------------
__global__ __launch_bounds__(256) void k_xphiT(
    const u16* __restrict__ Ah, const u16* __restrict__ Al,
    const u16* __restrict__ Bh, const u16* __restrict__ Bl,
    u16* __restrict__ outH, u16* __restrict__ outL, int N, int K) {
  __shared__ u16 lds[4 * 128 * 32];
  const int tid = threadIdx.x;
  const int w = tid >> 6, l = tid & 63;
  const int row0 = blockIdx.y * 128, col0 = blockIdx.x * 128;
  const int wm = (w >> 1) * 64, wn = (w & 1) * 64;
  const int lrow = l & 15, lk = (l >> 4) * 8;

  f32x4 zero4 = {0.f, 0.f, 0.f, 0.f};
  f32x4 acc[4][4];
#pragma unroll
  for (int i = 0; i < 4; ++i)
#pragma unroll
    for (int j = 0; j < 4; ++j) acc[i][j] = zero4;

  for (int k0 = 0; k0 < K; k0 += 32) {
    {
      const u16* gs[4] = {Ah, Al, Bh, Bl};
      const int r0s[4] = {row0, row0, col0, col0};
#pragma unroll
      for (int st = 0; st < 4; ++st) {
        u16* s = lds + st * 4096;
#pragma unroll
        for (int h = 0; h < 2; ++h) {
          int ch = h * 256 + w * 64 + l;
          const u16* gp = gs[st] + (size_t)(r0s[st] + (ch >> 2)) * K + k0 + (ch & 3) * 8;
          u16* sp = s + (h * 256 + w * 64) * 8;
          __builtin_amdgcn_global_load_lds((const __attribute__((address_space(1))) void*)gp,
                                           (__attribute__((address_space(3))) void*)sp, 16, 0, 0);
        }
      }
    }
    __syncthreads();
    short8 ah[4], al[4];
#pragma unroll
    for (int i = 0; i < 4; ++i) {
      int r = wm + i * 16 + lrow;
      ah[i] = *(const short8*)&lds[0 * 4096 + r * 32 + lk];
      al[i] = *(const short8*)&lds[1 * 4096 + r * 32 + lk];
    }
#pragma unroll
    for (int j = 0; j < 4; ++j) {
      int r = wn + j * 16 + lrow;
      short8 bh = *(const short8*)&lds[2 * 4096 + r * 32 + lk];
      short8 bl = *(const short8*)&lds[3 * 4096 + r * 32 + lk];
#pragma unroll
      for (int i = 0; i < 4; ++i) {
        acc[i][j] = __builtin_amdgcn_mfma_f32_16x16x32_bf16(ah[i], bh, acc[i][j], 0, 0, 0);
        acc[i][j] = __builtin_amdgcn_mfma_f32_16x16x32_bf16(ah[i], bl, acc[i][j], 0, 0, 0);
        acc[i][j] = __builtin_amdgcn_mfma_f32_16x16x32_bf16(al[i], bh, acc[i][j], 0, 0, 0);
      }
    }
    __syncthreads();
  }
#pragma unroll
  for (int i = 0; i < 4; ++i)
#pragma unroll
    for (int r = 0; r < 4; ++r) {
      int m = row0 + wm + i * 16 + ((l >> 4) << 2) + r;
      size_t base = (size_t)m * N;
#pragma unroll
      for (int j = 0; j < 4; ++j) {
        int n = col0 + wn + j * 16 + (l & 15);
        float v = acc[i][j][r];
        u16 hh = f2bf(v);
        outH[base + n] = hh;
        outL[base + n] = f2bf(v - bf2f(hh));
      }
    }
}

// ---------------- fp32 GEMMs (one-time: Gram, recon; proven r3) ----------------
#define BM 128
#define BN 128
#define BKK 16

__global__ __launch_bounds__(256) void k_gram_f32(const float* __restrict__ A,
                                                  const float* __restrict__ Bt,
                                                  float* __restrict__ C, int M, int N, int Kd) {
  __shared__ float As[BKK][BM + 4];
  __shared__ float Bs[BKK][BN + 4];
  int tx = threadIdx.x & 15, ty = threadIdx.x >> 4;
  int row0 = blockIdx.y * BM, col0 = blockIdx.x * BN;
  float acc[8][8] = {};
  for (int k0 = 0; k0 < Kd; k0 += BKK) {
#pragma unroll
    for (int i = 0; i < 2; ++i) {
      int f = threadIdx.x + 256 * i;
      int r = f >> 2, kk = (f & 3) << 2;
      float4 a = *(const float4*)&A[(size_t)(row0 + r) * Kd + k0 + kk];
      As[kk + 0][r] = a.x; As[kk + 1][r] = a.y; As[kk + 2][r] = a.z; As[kk + 3][r] = a.w;
      float4 b = *(const float4*)&Bt[(size_t)(col0 + r) * Kd + k0 + kk];
      Bs[kk + 0][r] = b.x; Bs[kk + 1][r] = b.y; Bs[kk + 2][r] = b.z; Bs[kk + 3][r] = b.w;
    }
    __syncthreads();
#pragma unroll
    for (int k = 0; k < BKK; ++k) {
      float a[8], b[8];
      *(float4*)&a[0] = *(const float4*)&As[k][ty * 8];
      *(float4*)&a[4] = *(const float4*)&As[k][ty * 8 + 4];
      *(float4*)&b[0] = *(const float4*)&Bs[k][tx * 8];
      *(float4*)&b[4] = *(const float4*)&Bs[k][tx * 8 + 4];
#pragma unroll
      for (int i = 0; i < 8; ++i)
#pragma unroll
        for (int j = 0; j < 8; ++j) acc[i][j] = fmaf(a[i], b[j], acc[i][j]);
    }
    __syncthreads();
  }
  int m0 = row0 + ty * 8, n0 = col0 + tx * 8;
#pragma unroll
  for (int i = 0; i < 8; ++i)
#pragma unroll
    for (int j4 = 0; j4 < 2; ++j4) {
      float4 c;
      c.x = acc[i][j4 * 4 + 0]; c.y = acc[i][j4 * 4 + 1];
      c.z = acc[i][j4 * 4 + 2]; c.w = acc[i][j4 * 4 + 3];
      *(float4*)&C[(size_t)(m0 + i) * N + n0 + j4 * 4] = c;
    }
}

__global__ __launch_bounds__(256) void k_recon_f32(const float* __restrict__ A,
                                                   const float* __restrict__ Bm,
                                                   float* __restrict__ C, int M, int N, int Kd) {
  __shared__ float As[BKK][BM + 4];
  __shared__ float Bs[BKK][BN + 4];
  int tx = threadIdx.x & 15, ty = threadIdx.x >> 4;
  int row0 = blockIdx.y * BM, col0 = blockIdx.x * BN;
  float acc[8][8] = {};
  for (int k0 = 0; k0 < Kd; k0 += BKK) {
#pragma unroll
    for (int i = 0; i < 2; ++i) {
      int f = threadIdx.x + 256 * i;
      int r = f >> 2, kk = (f & 3) << 2;
      float4 a = *(const float4*)&A[(size_t)(row0 + r) * Kd + k0 + kk];
      As[kk + 0][r] = a.x; As[kk + 1][r] = a.y; As[kk + 2][r] = a.z; As[kk + 3][r] = a.w;
      int kr = f >> 5, nc = (f & 31) << 2;
      *(float4*)&Bs[kr][nc] = *(const float4*)&Bm[(size_t)(k0 + kr) * N + col0 + nc];
    }
    __syncthreads();
#pragma unroll
    for (int k = 0; k < BKK; ++k) {
      float a[8], b[8];
      *(float4*)&a[0] = *(const float4*)&As[k][ty * 8];
      *(float4*)&a[4] = *(const float4*)&As[k][ty * 8 + 4];
      *(float4*)&b[0] = *(const float4*)&Bs[k][tx * 8];
      *(float4*)&b[4] = *(const float4*)&Bs[k][tx * 8 + 4];
#pragma unroll
      for (int i = 0; i < 8; ++i)
#pragma unroll
        for (int j = 0; j < 8; ++j) acc[i][j] = fmaf(a[i], b[j], acc[i][j]);
    }
    __syncthreads();
  }
  int m0 = row0 + ty * 8, n0 = col0 + tx * 8;
#pragma unroll
  for (int i = 0; i < 8; ++i)
#pragma unroll
    for (int j4 = 0; j4 < 2; ++j4) {
      float4 c;
      c.x = acc[i][j4 * 4 + 0]; c.y = acc[i][j4 * 4 + 1];
      c.z = acc[i][j4 * 4 + 2]; c.w = acc[i][j4 * 4 + 3];
      *(float4*)&C[(size_t)(m0 + i) * N + n0 + j4 * 4] = c;
    }
}

// ---------------- fused FISTA iteration (cooperative) ----------------
// fp16 1-term: acc = yh @ Gh over K' = 2048. y stored as single fp16
// (quantization noise 2^-11|y| on the EXTRAPOLATION point only; alpha is
// still prox'd exactly in fp32). -50% MFMA/LDS/A-staging vs r12's 2-term.
// Structure unchanged from r11/r12: 256x256 tile, BK=64, 8 waves,
// 1 barrier/tile, stage-first 1-tile-ahead prefetch into opposite buffer,
// T1 XCD remap, T2 swizzle, T5 setprio.

__device__ __forceinline__ void stage_op(const u16* src, int r0, int q0,
                                         u16* ldsbase, int tid) {
#pragma unroll
  for (int i = 0; i < 4; ++i) {
    int c = i * 512 + tid;
    int r = c >> 3;
    int sp = (c & 7) ^ (r & 7);
    const u16* gp = src + ((size_t)(r0 + r) << 11) + (q0 + (sp << 3));
    u16* lp = ldsbase + ((i * 512 + (tid & 448)) << 3);  // wave-uniform base
    __builtin_amdgcn_global_load_lds((const __attribute__((address_space(1))) void*)gp,
                                     (__attribute__((address_space(3))) void*)lp, 16, 0, 0);
  }
}

__global__ __launch_bounds__(512, 1) void k_fista_fused(
    u16* Yh,
    const u16* __restrict__ Gh,
    const u16* __restrict__ Cxh, const u16* __restrict__ Cxl, float* Alpha,
    const float* __restrict__ stepbuf, float mu) {
  __shared__ u16 lds[65536];  // 128 KB static: [buf][A 16384 u16 | B 16384 u16]

  const int tid = threadIdx.x;
  const int w = tid >> 6, l = tid & 63;
  const int wm = w >> 2, wn = w & 3;       // 2 x 4 waves
  const int lr = l & 15, lg = l >> 4;

  // XCD-aware remap (r9-verified: FETCH 595->332 MB/iter).
  const int lin = blockIdx.x + (int)gridDim.x * blockIdx.y;  // [0,256)
  const int bq = lin >> 6;          // [0,4)
  const int bp = (lin >> 3) & 7;    // [0,8)
  const int br = lin & 7;           // [0,8)
  const int row0 = ((bq << 3) + br) * 256;  // by = 8q + r
  const int col0 = bp * 256;                // bx = p

  f32x4 acc[8][4];
  f32x4 zero4 = {0.f, 0.f, 0.f, 0.f};
#pragma unroll
  for (int i = 0; i < 8; ++i)
#pragma unroll
    for (int j = 0; j < 4; ++j) acc[i][j] = zero4;

  // prologue: stage tile 0 into buf0 only (1-tile-ahead scheme)
  stage_op(Yh, row0, 0, lds, tid);
  stage_op(Gh, col0, 0, lds + 16384, tid);

#define FBODY(TT, B)                                                              \
  {                                                                               \
    asm volatile("s_waitcnt vmcnt(0)" ::: "memory");                              \
    __builtin_amdgcn_s_barrier();                                                 \
    __builtin_amdgcn_sched_barrier(0);                                            \
    {                                                                             \
      int tn = (TT) + 1;                                                          \
      if (tn >= NTILES) tn = 0;                                                   \
      int q0 = tn << 6;                                                           \
      stage_op(Yh, row0, q0, lds + ((B) ? 0 : 32768), tid);                       \
      stage_op(Gh, col0, q0, lds + ((B) ? 0 : 32768) + 16384, tid);               \
    }                                                                             \
    __builtin_amdgcn_sched_barrier(0);                                            \
    const u16* baseA = lds + ((B) ? 32768 : 0);                                   \
    const u16* baseB = baseA + 16384;                                             \
    short8 bf[4][2];                                                              \
    _Pragma("unroll") for (int j = 0; j < 4; ++j) {                               \
      _Pragma("unroll") for (int ks = 0; ks < 2; ++ks) {                          \
        int brow = wn * 64 + j * 16 + lr;                                         \
        int slot = ks * 4 + lg;                                                   \
        bf[j][ks] = *(const short8*)(baseB + brow * 64 + ((slot ^ (brow & 7)) << 3)); \
      }                                                                           \
    }                                                                             \
    __builtin_amdgcn_s_setprio(1);                                                \
    _Pragma("unroll") for (int i = 0; i < 8; ++i) {                               \
      int arow = wm * 128 + i * 16 + lr;                                          \
      short8 a0 = *(const short8*)(baseA + arow * 64 + (((0 + lg) ^ (arow & 7)) << 3)); \
      short8 a1 = *(const short8*)(baseA + arow * 64 + (((4 + lg) ^ (arow & 7)) << 3)); \
      _Pragma("unroll") for (int j = 0; j < 4; ++j) {                             \
        acc[i][j] = __builtin_amdgcn_mfma_f32_16x16x32_f16(a0, bf[j][0], acc[i][j], 0, 0, 0); \
        acc[i][j] = __builtin_amdgcn_mfma_f32_16x16x32_f16(a1, bf[j][1], acc[i][j], 0, 0, 0); \
      }                                                                           \
    }                                                                             \
    __builtin_amdgcn_s_setprio(0);                                                \
  }

  for (int tt = 0; tt < NTILES; tt += 2) {
    FBODY(tt, 0)
    FBODY(tt + 1, 1)
  }
#undef FBODY

  asm volatile("s_waitcnt vmcnt(0)" ::: "memory");
  cg::this_grid().sync();

  // ---- fused FISTA epilogue: each block updates only its own C-tile ----
  const float step = stepbuf[0];
  const float thr = LAM * step;
#pragma unroll
  for (int i = 0; i < 8; ++i) {
#pragma unroll
    for (int r = 0; r < 4; ++r) {
      int m = row0 + wm * 128 + i * 16 + (lg << 2) + r;
      size_t base = (size_t)m * KB;
#pragma unroll
      for (int j = 0; j < 4; ++j) {
        int n = col0 + wn * 64 + j * 16 + lr;
        size_t idx = base + n;
        float g = acc[i][j][r] - (bf2f(Cxh[idx]) + bf2f(Cxl[idx]));
        float y = h2f(Yh[idx]);
        float z = y - step * g;
        float az = fabsf(z) - thr;
        float a = az > 0.f ? copysignf(az, z) : 0.f;
        float ap = Alpha[idx];
        float yn = a + mu * (a - ap);
        Alpha[idx] = a;
        Yh[idx] = f2h(yn);
      }
    }
  }
}

// ---------------- launch ----------------
extern "C" void kernel_launch(void* const* d_in, const int* in_sizes, int n_in,
                              void* d_out, int out_size, void* d_ws, size_t ws_size,
                              hipStream_t stream) {
  const float* x = (const float*)d_in[0];    // [8192,1024]
  const float* phi = (const float*)d_in[1];  // [2048,1024]
  float* out = (float*)d_out;
  float* alpha = out;                             // [8192*2048] fp32, in-place FISTA state
  float* reconF = out + (size_t)BATCH * KB;       // [8192*1024] fp32 (33.55 MB scratch region)

  // ---- workspace layout (byte offsets) ----
  char* ws = (char*)d_ws;
  u16* Yh = (u16*)ws;                                   // 33,554,432 B (fp16, single)
  u16* Yl_unused = (u16*)(ws + 33554432ull);            // 33,554,432 B (free)
  u16* Gph = (u16*)(ws + 67108864ull);                  // 8,388,608 B  (Gh fp16; temp phiH bf16)
  u16* Gpl = (u16*)(ws + 75497472ull);                  // 8,388,608 B  (temp phiL bf16)
  u16* Cxh = (u16*)(ws + 83886080ull);                  // 33,554,432 B
  u16* Cxl = (u16*)(ws + 117440512ull);                 // 33,554,432 B
  float* stepbuf = (float*)(ws + 150994944ull);         // 64 B
  const size_t need = 150995008ull;
  if (ws_size < need) return;
  (void)Yl_unused;

  // pre-FISTA temporaries:
  float* Gf = (float*)Yh;           // G fp32 [2048][2048] = 16.78 MB, fits in Yh region
  u16* xh = (u16*)reconF;           // x split hi [8192*1024]
  u16* xl = xh + (size_t)BATCH * DD;
  float* vbuf = reconF;             // power-iter scratch (after Cx done, xh/xl dead)
  float* wbuf = reconF + 2048;
  float* normPart = reconF + 4096;  // 50*64
  float* LPart = reconF + 7296;     // 64

  // 1. splits: phi -> (Gph,Gpl temp, bf16), x -> (xh,xl in recon region)
  k_split_f32<<<2048, 256, 0, stream>>>(phi, Gph, Gpl, KB * DD);
  k_split_f32<<<2048, 256, 0, stream>>>(x, xh, xl, BATCH * DD);

  // 2. Cx = x @ phi^T (bf16-pair out), M=8192 N=2048 K=1024
  k_xphiT<<<dim3(KB / 128, BATCH / 128), 256, 0, stream>>>(xh, xl, Gph, Gpl, Cxh, Cxl, KB, DD);

  // 3. G = phi @ phi^T (fp32) into Yh region
  k_gram_f32<<<dim3(KB / BN, KB / BM), 256, 0, stream>>>(phi, phi, Gf, KB, KB, DD);

  // 4. power iteration -> step = 1/L  (scratch in recon region; xh/xl dead)
  k_init_v<<<8, 256, 0, stream>>>(vbuf);
  for (int s = 0; s < N_POWER; ++s) {
    k_power_matvec<0><<<64, 256, 0, stream>>>(Gf, vbuf, wbuf, normPart + s * 64);
    k_power_scale<<<KB / 256, 256, 0, stream>>>(wbuf, vbuf, normPart + s * 64);
  }
  k_power_matvec<1><<<64, 256, 0, stream>>>(Gf, vbuf, wbuf, LPart);
  k_compute_step<<<1, 1, 0, stream>>>(LPart, stepbuf);

  // 5. Gh = fp16(G) (overwrites phiH split; it is dead after Cx)
  k_cvt_f16<<<2048, 256, 0, stream>>>(Gf, Gph, KB * KB);

  // 6. zero Yh (kills G) and alpha
  k_zero2<<<2048, 256, 0, stream>>>((float4*)Yh, (int)(33554432 / 16),
                                    (float4*)alpha, (int)(67108864 / 16));

  // 7. FISTA: 100 cooperative fused iterations
  float t = 1.f;
  float mus[N_ITER];
  for (int it = 0; it < N_ITER; ++it) {
    float tn = 0.5f * (1.f + sqrtf(1.f + 4.f * t * t));
    mus[it] = (t - 1.f) / tn;
    t = tn;
  }
  u16* pYh = Yh;
  const u16* pGh = Gph;
  const u16 *pCxh = Cxh, *pCxl = Cxl;
  float* pAl = alpha;
  const float* pStep = stepbuf;
  for (int it = 0; it < N_ITER; ++it) {
    void* kargs[7] = {&pYh, &pGh, &pCxh, &pCxl, &pAl, &pStep, &mus[it]};
    (void)hipLaunchCooperativeKernel((const void*)k_fista_fused, dim3(KB / 256, BATCH / 256),
                                     dim3(512), kargs, 0, stream);
  }

  // 8. recon = alpha @ phi (fp32; overwrites recon-region scratch)
  k_recon_f32<<<dim3(DD / BN, BATCH / BM), 256, 0, stream>>>(
      alpha, phi, reconF, BATCH, DD, KB);
}

// Round 17
// 14439.850 us; speedup vs baseline: 2.0562x; 1.0255x over previous
//
#include <hip/hip_runtime.h>
#include <hip/hip_cooperative_groups.h>
#include <math.h>

namespace cg = cooperative_groups;

#define BATCH 8192
#define KB 2048      // num basis (N of fused GEMM)
#define DD 1024      // dim basis
#define LAM 0.1f
#define N_ITER 100
#define N_POWER 50
#define NTILES 32    // K' = 2048 = 32 * 64  (fp16 1-term: yh vs Gh)

typedef unsigned short u16;
using short8 = __attribute__((ext_vector_type(8))) short;
using f32x4  = __attribute__((ext_vector_type(4))) float;

// ---------- bf16 split helpers (RNE) ----------
__device__ __forceinline__ u16 f2bf(float f) {
  unsigned int u = __builtin_bit_cast(unsigned int, f);
  u = u + 0x7FFFu + ((u >> 16) & 1u);
  return (u16)(u >> 16);
}
__device__ __forceinline__ float bf2f(u16 s) {
  unsigned int u = ((unsigned int)s) << 16;
  return __builtin_bit_cast(float, u);
}

// ---------- fp16 helpers (RNE via HW cvt) ----------
__device__ __forceinline__ u16 f2h(float f) {
  _Float16 h = (_Float16)f;
  return __builtin_bit_cast(unsigned short, h);
}
__device__ __forceinline__ float h2f(u16 s) {
  _Float16 h = __builtin_bit_cast(_Float16, s);
  return (float)h;
}

// ---------------- utility kernels ----------------
__global__ void k_split_f32(const float* __restrict__ in, u16* __restrict__ h,
                            u16* __restrict__ lo, int n) {  // bf16 pair
  for (int i = blockIdx.x * blockDim.x + threadIdx.x; i < n; i += gridDim.x * blockDim.x) {
    float v = in[i];
    u16 hh = f2bf(v);
    h[i] = hh;
    lo[i] = f2bf(v - bf2f(hh));
  }
}

__global__ void k_cvt_f16(const float* __restrict__ in, u16* __restrict__ h, int n) {
  for (int i = blockIdx.x * blockDim.x + threadIdx.x; i < n; i += gridDim.x * blockDim.x)
    h[i] = f2h(in[i]);
}

__global__ void k_zero2(float4* __restrict__ a, int na, float4* __restrict__ b, int nb) {
  float4 z = {0.f, 0.f, 0.f, 0.f};
  for (int i = blockIdx.x * blockDim.x + threadIdx.x; i < na; i += gridDim.x * blockDim.x)
    a[i] = z;
  for (int i = blockIdx.x * blockDim.x + threadIdx.x; i < nb; i += gridDim.x * blockDim.x)
    b[i] = z;
}

__global__ void k_init_v(float* __restrict__ v) {
  int i = blockIdx.x * blockDim.x + threadIdx.x;
  if (i < KB) v[i] = 1.f;
}

// ---------------- power iteration (proven r3) ----------------
template <int MODE>
__global__ __launch_bounds__(256) void k_power_matvec(const float* __restrict__ G,
                                                      const float* __restrict__ vin,
                                                      float* __restrict__ wout,
                                                      float* __restrict__ partial) {
  int rloc = threadIdx.x >> 3;
  int seg = threadIdx.x & 7;
  int row = blockIdx.x * 32 + rloc;
  const float* g = G + (size_t)row * KB + seg * 256;
  const float* vv = vin + seg * 256;
  float s = 0.f;
#pragma unroll 8
  for (int j = 0; j < 256; j += 4) {
    float4 gg = *(const float4*)(g + j);
    float4 vx = *(const float4*)(vv + j);
    s = fmaf(gg.x, vx.x, fmaf(gg.y, vx.y, fmaf(gg.z, vx.z, fmaf(gg.w, vx.w, s))));
  }
#pragma unroll
  for (int off = 1; off < 8; off <<= 1) s += __shfl_xor(s, off, 64);
  if (seg == 0) wout[row] = s;
  float val = (seg == 0) ? (MODE ? vin[row] * s : s * s) : 0.f;
#pragma unroll
  for (int off = 8; off < 64; off <<= 1) val += __shfl_xor(val, off, 64);
  __shared__ float red[4];
  int lane = threadIdx.x & 63, wid = threadIdx.x >> 6;
  if (lane == 0) red[wid] = val;
  __syncthreads();
  if (threadIdx.x == 0) partial[blockIdx.x] = red[0] + red[1] + red[2] + red[3];
}

__global__ void k_power_scale(const float* __restrict__ w, float* __restrict__ v,
                              const float* __restrict__ partial) {
  float n2 = 0.f;
#pragma unroll
  for (int i = 0; i < 64; ++i) n2 += partial[i];
  int i = blockIdx.x * 256 + threadIdx.x;
  v[i] = w[i] / sqrtf(n2);
}

__global__ void k_compute_step(const float* __restrict__ partialL, float* __restrict__ stepbuf) {
  float L = 0.f;
#pragma unroll
  for (int i = 0; i < 64; ++i) L += partialL[i];
  stepbuf[0] = 1.f / L;
}

// ---------------- split-bf16 MFMA GEMM: C = A @ B^T (r3-proven body) ----------------
// EPI 0: out16[m*N+n] = fp16(acc)   (Cx)
// EPI 1: out32[m*N+n] = acc         (Gram, fp32 for power iteration)
template <int EPI>
__global__ __launch_bounds__(256) void k_xphiT(
    const u16* __restrict__ Ah, const u16* __restrict__ Al,
    const u16* __restrict__ Bh, const u16* __restrict__ Bl,
    u16* __restrict__ out16, float* __restrict__ out32, int N, int K) {
  __shared__ u16 lds[4 * 128 * 32];
  const int tid = threadIdx.x;
  const int w = tid >> 6, l = tid & 63;
  const int row0 = blockIdx.y * 128, col0 = blockIdx.x * 128;
  const int wm = (w >> 1) * 64, wn = (w & 1) * 64;
  const int lrow = l & 15, lk = (l >> 4) * 8;

  f32x4 zero4 = {0.f, 0.f, 0.f, 0.f};
  f32x4 acc[4][4];
#pragma unroll
  for (int i = 0; i < 4; ++i)
#pragma unroll
    for (int j = 0; j < 4; ++j) acc[i][j] = zero4;

  for (int k0 = 0; k0 < K; k0 += 32) {
    {
      const u16* gs[4] = {Ah, Al, Bh, Bl};
      const int r0s[4] = {row0, row0, col0, col0};
#pragma unroll
      for (int st = 0; st < 4; ++st) {
        u16* s = lds + st * 4096;
#pragma unroll
        for (int h = 0; h < 2; ++h) {
          int ch = h * 256 + w * 64 + l;
          const u16* gp = gs[st] + (size_t)(r0s[st] + (ch >> 2)) * K + k0 + (ch & 3) * 8;
          u16* sp = s + (h * 256 + w * 64) * 8;
          __builtin_amdgcn_global_load_lds((const __attribute__((address_space(1))) void*)gp,
                                           (__attribute__((address_space(3))) void*)sp, 16, 0, 0);
        }
      }
    }
    __syncthreads();
    short8 ah[4], al[4];
#pragma unroll
    for (int i = 0; i < 4; ++i) {
      int r = wm + i * 16 + lrow;
      ah[i] = *(const short8*)&lds[0 * 4096 + r * 32 + lk];
      al[i] = *(const short8*)&lds[1 * 4096 + r * 32 + lk];
    }
#pragma unroll
    for (int j = 0; j < 4; ++j) {
      int r = wn + j * 16 + lrow;
      short8 bh = *(const short8*)&lds[2 * 4096 + r * 32 + lk];
      short8 bl = *(const short8*)&lds[3 * 4096 + r * 32 + lk];
#pragma unroll
      for (int i = 0; i < 4; ++i) {
        acc[i][j] = __builtin_amdgcn_mfma_f32_16x16x32_bf16(ah[i], bh, acc[i][j], 0, 0, 0);
        acc[i][j] = __builtin_amdgcn_mfma_f32_16x16x32_bf16(ah[i], bl, acc[i][j], 0, 0, 0);
        acc[i][j] = __builtin_amdgcn_mfma_f32_16x16x32_bf16(al[i], bh, acc[i][j], 0, 0, 0);
      }
    }
    __syncthreads();
  }
#pragma unroll
  for (int i = 0; i < 4; ++i)
#pragma unroll
    for (int r = 0; r < 4; ++r) {
      int m = row0 + wm + i * 16 + ((l >> 4) << 2) + r;
      size_t base = (size_t)m * N;
#pragma unroll
      for (int j = 0; j < 4; ++j) {
        int n = col0 + wn + j * 16 + (l & 15);
        float v = acc[i][j][r];
        if (EPI == 0) {
          out16[base + n] = f2h(v);
        } else {
          out32[base + n] = v;
        }
      }
    }
}

// ---------------- fp32 recon GEMM (one-time; proven r3) ----------------
#define BM 128
#define BN 128
#define BKK 16

__global__ __launch_bounds__(256) void k_recon_f32(const float* __restrict__ A,
                                                   const float* __restrict__ Bm,
                                                   float* __restrict__ C, int M, int N, int Kd) {
  __shared__ float As[BKK][BM + 4];
  __shared__ float Bs[BKK][BN + 4];
  int tx = threadIdx.x & 15, ty = threadIdx.x >> 4;
  int row0 = blockIdx.y * BM, col0 = blockIdx.x * BN;
  float acc[8][8] = {};
  for (int k0 = 0; k0 < Kd; k0 += BKK) {
#pragma unroll
    for (int i = 0; i < 2; ++i) {
      int f = threadIdx.x + 256 * i;
      int r = f >> 2, kk = (f & 3) << 2;
      float4 a = *(const float4*)&A[(size_t)(row0 + r) * Kd + k0 + kk];
      As[kk + 0][r] = a.x; As[kk + 1][r] = a.y; As[kk + 2][r] = a.z; As[kk + 3][r] = a.w;
      int kr = f >> 5, nc = (f & 31) << 2;
      *(float4*)&Bs[kr][nc] = *(const float4*)&Bm[(size_t)(k0 + kr) * N + col0 + nc];
    }
    __syncthreads();
#pragma unroll
    for (int k = 0; k < BKK; ++k) {
      float a[8], b[8];
      *(float4*)&a[0] = *(const float4*)&As[k][ty * 8];
      *(float4*)&a[4] = *(const float4*)&As[k][ty * 8 + 4];
      *(float4*)&b[0] = *(const float4*)&Bs[k][tx * 8];
      *(float4*)&b[4] = *(const float4*)&Bs[k][tx * 8 + 4];
#pragma unroll
      for (int i = 0; i < 8; ++i)
#pragma unroll
        for (int j = 0; j < 8; ++j) acc[i][j] = fmaf(a[i], b[j], acc[i][j]);
    }
    __syncthreads();
  }
  int m0 = row0 + ty * 8, n0 = col0 + tx * 8;
#pragma unroll
  for (int i = 0; i < 8; ++i)
#pragma unroll
    for (int j4 = 0; j4 < 2; ++j4) {
      float4 c;
      c.x = acc[i][j4 * 4 + 0]; c.y = acc[i][j4 * 4 + 1];
      c.z = acc[i][j4 * 4 + 2]; c.w = acc[i][j4 * 4 + 3];
      *(float4*)&C[(size_t)(m0 + i) * N + n0 + j4 * 4] = c;
    }
}

// ---------------- fused FISTA iteration (cooperative) ----------------
// fp16 1-term GEMM (r16-proven) + lean epilogue:
//   alpha kept as fp16 in ws during the loop (momentum history quantized,
//   same error class as the y-fp16 storage already absorbed); the fp32
//   alpha output is written ONLY on the last iteration from the
//   register-exact prox. Cx read as single fp16 (fixed 2^-11 perturbation
//   of the constant gradient term, same class as Gh).
// Epilogue traffic: 268 -> ~134 MB/iter.

__device__ __forceinline__ void stage_op(const u16* src, int r0, int q0,
                                         u16* ldsbase, int tid) {
#pragma unroll
  for (int i = 0; i < 4; ++i) {
    int c = i * 512 + tid;
    int r = c >> 3;
    int sp = (c & 7) ^ (r & 7);
    const u16* gp = src + ((size_t)(r0 + r) << 11) + (q0 + (sp << 3));
    u16* lp = ldsbase + ((i * 512 + (tid & 448)) << 3);  // wave-uniform base
    __builtin_amdgcn_global_load_lds((const __attribute__((address_space(1))) void*)gp,
                                     (__attribute__((address_space(3))) void*)lp, 16, 0, 0);
  }
}

__global__ __launch_bounds__(512, 1) void k_fista_fused(
    u16* Yh, u16* Af16,
    const u16* __restrict__ Gh,
    const u16* __restrict__ Cx, float* AlphaOut,
    const float* __restrict__ stepbuf, float mu, int last) {
  __shared__ u16 lds[65536];  // 128 KB static: [buf][A 16384 u16 | B 16384 u16]

  const int tid = threadIdx.x;
  const int w = tid >> 6, l = tid & 63;
  const int wm = w >> 2, wn = w & 3;       // 2 x 4 waves
  const int lr = l & 15, lg = l >> 4;

  // XCD-aware remap (r9-verified: FETCH 595->332 MB/iter).
  const int lin = blockIdx.x + (int)gridDim.x * blockIdx.y;  // [0,256)
  const int bq = lin >> 6;          // [0,4)
  const int bp = (lin >> 3) & 7;    // [0,8)
  const int br = lin & 7;           // [0,8)
  const int row0 = ((bq << 3) + br) * 256;  // by = 8q + r
  const int col0 = bp * 256;                // bx = p

  f32x4 acc[8][4];
  f32x4 zero4 = {0.f, 0.f, 0.f, 0.f};
#pragma unroll
  for (int i = 0; i < 8; ++i)
#pragma unroll
    for (int j = 0; j < 4; ++j) acc[i][j] = zero4;

  // prologue: stage tile 0 into buf0 only (1-tile-ahead scheme)
  stage_op(Yh, row0, 0, lds, tid);
  stage_op(Gh, col0, 0, lds + 16384, tid);

#define FBODY(TT, B)                                                              \
  {                                                                               \
    asm volatile("s_waitcnt vmcnt(0)" ::: "memory");                              \
    __builtin_amdgcn_s_barrier();                                                 \
    __builtin_amdgcn_sched_barrier(0);                                            \
    {                                                                             \
      int tn = (TT) + 1;                                                          \
      if (tn >= NTILES) tn = 0;                                                   \
      int q0 = tn << 6;                                                           \
      stage_op(Yh, row0, q0, lds + ((B) ? 0 : 32768), tid);                       \
      stage_op(Gh, col0, q0, lds + ((B) ? 0 : 32768) + 16384, tid);               \
    }                                                                             \
    __builtin_amdgcn_sched_barrier(0);                                            \
    const u16* baseA = lds + ((B) ? 32768 : 0);                                   \
    const u16* baseB = baseA + 16384;                                             \
    short8 bf[4][2];                                                              \
    _Pragma("unroll") for (int j = 0; j < 4; ++j) {                               \
      _Pragma("unroll") for (int ks = 0; ks < 2; ++ks) {                          \
        int brow = wn * 64 + j * 16 + lr;                                         \
        int slot = ks * 4 + lg;                                                   \
        bf[j][ks] = *(const short8*)(baseB + brow * 64 + ((slot ^ (brow & 7)) << 3)); \
      }                                                                           \
    }                                                                             \
    __builtin_amdgcn_s_setprio(1);                                                \
    _Pragma("unroll") for (int i = 0; i < 8; ++i) {                               \
      int arow = wm * 128 + i * 16 + lr;                                          \
      short8 a0 = *(const short8*)(baseA + arow * 64 + (((0 + lg) ^ (arow & 7)) << 3)); \
      short8 a1 = *(const short8*)(baseA + arow * 64 + (((4 + lg) ^ (arow & 7)) << 3)); \
      _Pragma("unroll") for (int j = 0; j < 4; ++j) {                             \
        acc[i][j] = __builtin_amdgcn_mfma_f32_16x16x32_f16(a0, bf[j][0], acc[i][j], 0, 0, 0); \
        acc[i][j] = __builtin_amdgcn_mfma_f32_16x16x32_f16(a1, bf[j][1], acc[i][j], 0, 0, 0); \
      }                                                                           \
    }                                                                             \
    __builtin_amdgcn_s_setprio(0);                                                \
  }

  for (int tt = 0; tt < NTILES; tt += 2) {
    FBODY(tt, 0)
    FBODY(tt + 1, 1)
  }
#undef FBODY

  asm volatile("s_waitcnt vmcnt(0)" ::: "memory");
  cg::this_grid().sync();

  // ---- fused FISTA epilogue: each block updates only its own C-tile ----
  const float step = stepbuf[0];
  const float thr = LAM * step;
#pragma unroll
  for (int i = 0; i < 8; ++i) {
#pragma unroll
    for (int r = 0; r < 4; ++r) {
      int m = row0 + wm * 128 + i * 16 + (lg << 2) + r;
      size_t base = (size_t)m * KB;
#pragma unroll
      for (int j = 0; j < 4; ++j) {
        int n = col0 + wn * 64 + j * 16 + lr;
        size_t idx = base + n;
        float g = acc[i][j][r] - h2f(Cx[idx]);
        float y = h2f(Yh[idx]);
        float z = y - step * g;
        float az = fabsf(z) - thr;
        float a = az > 0.f ? copysignf(az, z) : 0.f;
        float ap = h2f(Af16[idx]);
        float yn = a + mu * (a - ap);
        Af16[idx] = f2h(a);
        if (last) AlphaOut[idx] = a;
        Yh[idx] = f2h(yn);
      }
    }
  }
}

// ---------------- launch ----------------
extern "C" void kernel_launch(void* const* d_in, const int* in_sizes, int n_in,
                              void* d_out, int out_size, void* d_ws, size_t ws_size,
                              hipStream_t stream) {
  const float* x = (const float*)d_in[0];    // [8192,1024]
  const float* phi = (const float*)d_in[1];  // [2048,1024]
  float* out = (float*)d_out;
  float* alpha = out;                             // [8192*2048] fp32, written at last iter
  float* reconF = out + (size_t)BATCH * KB;       // [8192*1024] fp32 (33.55 MB scratch region)

  // ---- workspace layout (byte offsets) ----
  char* ws = (char*)d_ws;
  u16* Yh = (u16*)ws;                                   // 33,554,432 B (fp16 y)
  u16* Af16 = (u16*)(ws + 33554432ull);                 // 33,554,432 B (fp16 alpha history)
  u16* Gph = (u16*)(ws + 67108864ull);                  // 8,388,608 B  (Gh fp16; temp phiH bf16)
  u16* Gpl = (u16*)(ws + 75497472ull);                  // 8,388,608 B  (temp phiL bf16)
  u16* Cx16 = (u16*)(ws + 83886080ull);                 // 33,554,432 B (fp16 Cx)
  float* Gf = (float*)(ws + 117440512ull);              // 16,777,216 B (fp32 G for power iter)
  float* stepbuf = (float*)(ws + 150994944ull);         // 64 B
  const size_t need = 150995008ull;
  if (ws_size < need) return;

  // pre-FISTA temporaries in recon region of d_out:
  u16* xh = (u16*)reconF;           // x split hi [8192*1024]
  u16* xl = xh + (size_t)BATCH * DD;
  float* vbuf = reconF;             // power-iter scratch (xh/xl dead after Cx)
  float* wbuf = reconF + 2048;
  float* normPart = reconF + 4096;  // 50*64
  float* LPart = reconF + 7296;     // 64

  // 1. splits: phi -> (Gph,Gpl temp, bf16 pair), x -> (xh,xl)
  k_split_f32<<<2048, 256, 0, stream>>>(phi, Gph, Gpl, KB * DD);
  k_split_f32<<<2048, 256, 0, stream>>>(x, xh, xl, BATCH * DD);

  // 2. Cx = x @ phi^T (fp16 out), M=8192 N=2048 K=1024
  k_xphiT<0><<<dim3(KB / 128, BATCH / 128), 256, 0, stream>>>(
      xh, xl, Gph, Gpl, Cx16, nullptr, KB, DD);

  // 3. G = phi @ phi^T (fp32 out via MFMA), M=N=2048 K=1024
  k_xphiT<1><<<dim3(KB / 128, KB / 128), 256, 0, stream>>>(
      Gph, Gpl, Gph, Gpl, nullptr, Gf, KB, DD);

  // 4. power iteration -> step = 1/L
  k_init_v<<<8, 256, 0, stream>>>(vbuf);
  for (int s = 0; s < N_POWER; ++s) {
    k_power_matvec<0><<<64, 256, 0, stream>>>(Gf, vbuf, wbuf, normPart + s * 64);
    k_power_scale<<<KB / 256, 256, 0, stream>>>(wbuf, vbuf, normPart + s * 64);
  }
  k_power_matvec<1><<<64, 256, 0, stream>>>(Gf, vbuf, wbuf, LPart);
  k_compute_step<<<1, 1, 0, stream>>>(LPart, stepbuf);

  // 5. Gh = fp16(G) (overwrites phiH split; dead after steps 2-3)
  k_cvt_f16<<<2048, 256, 0, stream>>>(Gf, Gph, KB * KB);

  // 6. zero Yh and Af16
  k_zero2<<<2048, 256, 0, stream>>>((float4*)Yh, (int)(33554432 / 16),
                                    (float4*)Af16, (int)(33554432 / 16));

  // 7. FISTA: 100 cooperative fused iterations
  float t = 1.f;
  float mus[N_ITER];
  int lasts[N_ITER];
  for (int it = 0; it < N_ITER; ++it) {
    float tn = 0.5f * (1.f + sqrtf(1.f + 4.f * t * t));
    mus[it] = (t - 1.f) / tn;
    lasts[it] = (it == N_ITER - 1) ? 1 : 0;
    t = tn;
  }
  u16 *pYh = Yh, *pAf = Af16;
  const u16* pGh = Gph;
  const u16* pCx = Cx16;
  float* pAl = alpha;
  const float* pStep = stepbuf;
  for (int it = 0; it < N_ITER; ++it) {
    void* kargs[8] = {&pYh, &pAf, &pGh, &pCx, &pAl, &pStep, &mus[it], &lasts[it]};
    (void)hipLaunchCooperativeKernel((const void*)k_fista_fused, dim3(KB / 256, BATCH / 256),
                                     dim3(512), kargs, 0, stream);
  }

  // 8. recon = alpha @ phi (fp32; overwrites recon-region scratch)
  k_recon_f32<<<dim3(DD / BN, BATCH / BM), 256, 0, stream>>>(
      alpha, phi, reconF, BATCH, DD, KB);
}